// Round 1
// baseline (41209.174 us; speedup 1.0000x reference)
//
#include <hip/hip_runtime.h>
#include <hip/hip_bf16.h>

// Problem constants
constexpr int kB  = 128;   // batch
constexpr int kW  = 64;    // time steps
constexpr int kM  = 512;   // "major" dim
constexpr int kH  = 64;    // GRU hidden
constexpr int kC  = 4;
constexpr int kLR = 16;
constexpr int kRD = 32;
constexpr int kD  = 128;   // L*H
constexpr int kNC = kB * kM;      // 65536 cells
constexpr int kR  = kD * kB;      // 16384 GEMM rows
constexpr int kNcat = kM + kC * kLR;  // 576 GEMM cols (G | Aw^T)

__device__ __forceinline__ float sigmf(float v) { return 1.f / (1.f + __expf(-v)); }
__device__ __forceinline__ float tanhf2(float v) { float e = __expf(2.f * v); return 1.f - 2.f / (e + 1.f); }

// ---------------- prologue kernels ----------------

// HNT[j][cell] = H_init[0, m, j]   (cell = b*512 + m)
__global__ void k_init_hnt(const float* __restrict__ Hini, float* __restrict__ HNT) {
    int id = blockIdx.x * 256 + threadIdx.x;          // 64*65536 total
    int cell = id & (kNC - 1);
    int j = id >> 16;
    int m = cell & (kM - 1);
    HNT[id] = Hini[m * kH + j];
}

// gh1T[k][m] = bh1[k] + sum_j H_init[1,m,j] * wh1[k,j]
__global__ void k_gh1T(const float* __restrict__ Hini, const float* __restrict__ wh1,
                       const float* __restrict__ bh1, float* __restrict__ gh1T) {
    int id = blockIdx.x * 256 + threadIdx.x;          // 192*512
    int k = id >> 9, m = id & (kM - 1);
    float acc = bh1[k];
    #pragma unroll
    for (int j = 0; j < kH; j++)
        acc = fmaf(Hini[(kM + m) * kH + j], wh1[k * kH + j], acc);
    gh1T[id] = acc;
}

// H1T[i][m] = H_init[1, m, i]
__global__ void k_h1T(const float* __restrict__ Hini, float* __restrict__ H1T) {
    int id = blockIdx.x * 256 + threadIdx.x;          // 64*512
    int i = id >> 9, m = id & (kM - 1);
    H1T[id] = Hini[(kM + m) * kH + i];
}

// Bcat[m][n] = G[m][n] for n<512
__global__ void k_copyG(const float* __restrict__ G, float* __restrict__ Bcat) {
    int id = blockIdx.x * 256 + threadIdx.x;          // 512*512
    int r = id >> 9, n = id & (kM - 1);
    Bcat[r * kNcat + n] = G[id];
}

// weight-norm A: Bcat[m][512+cl] = A_g[cl]*A_v[cl][m]/||A_v[cl,:]||
__global__ void k_norm_aw(const float* __restrict__ Av, const float* __restrict__ Ag,
                          float* __restrict__ Bcat) {
    int row = blockIdx.x;        // 0..63 = c*16+l
    int lane = threadIdx.x;      // 64
    float v[8]; float s = 0.f;
    #pragma unroll
    for (int q = 0; q < 8; q++) { v[q] = Av[row * kM + q * 64 + lane]; s += v[q] * v[q]; }
    #pragma unroll
    for (int off = 32; off > 0; off >>= 1) s += __shfl_down(s, off);
    s = __shfl(s, 0);
    float scale = Ag[row] / sqrtf(s);
    #pragma unroll
    for (int q = 0; q < 8; q++)
        Bcat[(q * 64 + lane) * kNcat + kM + row] = v[q] * scale;
}

// weight-norm B: BwN[c*512+m][l]
__global__ void k_norm_bw(const float* __restrict__ Bv, const float* __restrict__ Bg,
                          float* __restrict__ BwN) {
    int row = blockIdx.x * 256 + threadIdx.x;   // 0..2047
    float v[16]; float s = 0.f;
    #pragma unroll
    for (int l = 0; l < 16; l++) { v[l] = Bv[row * 16 + l]; s += v[l] * v[l]; }
    float scale = Bg[row] / sqrtf(s);
    #pragma unroll
    for (int l = 0; l < 16; l++) BwN[row * 16 + l] = v[l] * scale;
}

// weight-norm C, transposed: CwT[(c*128+d)*32 + r]
__global__ void k_norm_cw(const float* __restrict__ Cv, const float* __restrict__ Cg,
                          float* __restrict__ CwT) {
    int row = blockIdx.x;        // 0..127 = c*32+r
    int lane = threadIdx.x;      // 64
    int c = row >> 5, r = row & 31;
    float v0 = Cv[row * kD + lane], v1 = Cv[row * kD + 64 + lane];
    float s = v0 * v0 + v1 * v1;
    #pragma unroll
    for (int off = 32; off > 0; off >>= 1) s += __shfl_down(s, off);
    s = __shfl(s, 0);
    float scale = Cg[row] / sqrtf(s);
    CwT[(c * kD + lane) * kRD + r] = v0 * scale;
    CwT[(c * kD + 64 + lane) * kRD + r] = v1 * scale;
}

// ---------------- GRU step ----------------
// thread-per-cell; weights read uniformly (scalar pipe); h1 via column-private LDS.
__global__ __launch_bounds__(256) void k_gru(
    const float* __restrict__ x, const float* __restrict__ wx0,
    const float* __restrict__ wh0, const float* __restrict__ bx0,
    const float* __restrict__ bh0, const float* __restrict__ wx1,
    const float* __restrict__ bx1, const float* __restrict__ gh1T,
    const float* __restrict__ H1T, float* __restrict__ HNT,
    float* __restrict__ XPT, int t)
{
    __shared__ float h1s[64][256];
    const int tid = threadIdx.x;
    const int cell = blockIdx.x * 256 + tid;
    const int b = cell >> 9, m = cell & (kM - 1);

    float hpr[64];
    #pragma unroll
    for (int j = 0; j < 64; j++) hpr[j] = HNT[j * kNC + cell];
    const float xv = x[(b * kW + t) * kM + m];

    // GRU layer 0
    #pragma unroll 1
    for (int i = 0; i < 64; i++) {
        float gr  = bh0[i]       + bx0[i]       + xv * wx0[i];
        float gz  = bh0[64 + i]  + bx0[64 + i]  + xv * wx0[64 + i];
        float gnh = bh0[128 + i];
        float gnx = bx0[128 + i] + xv * wx0[128 + i];
        const float* wr = wh0 + i * 64;
        const float* wz = wh0 + (64 + i) * 64;
        const float* wn = wh0 + (128 + i) * 64;
        #pragma unroll
        for (int j = 0; j < 64; j++) {
            float h = hpr[j];
            gr  = fmaf(wr[j], h, gr);
            gz  = fmaf(wz[j], h, gz);
            gnh = fmaf(wn[j], h, gnh);
        }
        float r = sigmf(gr), z = sigmf(gz);
        float n = tanhf2(gnx + r * gnh);
        float hi = HNT[i * kNC + cell];      // dynamic-index read of hp[i]
        float h1 = n + z * (hi - n);
        h1s[i][tid] = h1;
        XPT[i * kNC + cell] = h1;
    }
    // GRU layer 1 (hidden side fixed: gh1T precomputed)
    #pragma unroll 1
    for (int i = 0; i < 64; i++) {
        float gr  = bx1[i]       + gh1T[i * kM + m];
        float gz  = bx1[64 + i]  + gh1T[(64 + i) * kM + m];
        float gnh =                gh1T[(128 + i) * kM + m];
        float gnx = bx1[128 + i];
        const float* wr = wx1 + i * 64;
        const float* wz = wx1 + (64 + i) * 64;
        const float* wn = wx1 + (128 + i) * 64;
        #pragma unroll
        for (int j = 0; j < 64; j++) {
            float h = h1s[j][tid];
            gr  = fmaf(wr[j], h, gr);
            gz  = fmaf(wz[j], h, gz);
            gnx = fmaf(wn[j], h, gnx);
        }
        float r = sigmf(gr), z = sigmf(gz);
        float n = tanhf2(gnx + r * gnh);
        float h01 = H1T[i * kM + m];
        float h2 = n + z * (h01 - n);
        XPT[(64 + i) * kNC + cell] = h2;
        HNT[i * kNC + cell] = h2;
    }
}

// ---------------- GEMM: [16384 x 512] @ [512 x 576] ----------------
// cols 0..511 -> relu -> XP0 ; cols 512..575 -> +A_b -> Abuf
__global__ __launch_bounds__(256) void k_gemm(
    const float* __restrict__ X, const float* __restrict__ Bc,
    const float* __restrict__ Ab, float* __restrict__ XP0,
    float* __restrict__ Abuf)
{
    __shared__ float As[32][132];
    __shared__ float Bs[32][64];
    const int tid = threadIdx.x;
    const int r0 = blockIdx.x * 128;
    const int ct = blockIdx.y;
    const int c0 = ct * 64;
    const int tx = tid & 15, ty = tid >> 4;
    float acc[8][4] = {};

    for (int kk = 0; kk < 512; kk += 32) {
        __syncthreads();
        #pragma unroll
        for (int it = 0; it < 4; it++) {
            int id = it * 256 + tid;              // 1024 float4
            int ri = id >> 3, k4 = id & 7;
            float4 v = *(const float4*)&X[(r0 + ri) * kM + kk + k4 * 4];
            As[k4 * 4 + 0][ri] = v.x; As[k4 * 4 + 1][ri] = v.y;
            As[k4 * 4 + 2][ri] = v.z; As[k4 * 4 + 3][ri] = v.w;
        }
        #pragma unroll
        for (int it = 0; it < 2; it++) {
            int id = it * 256 + tid;              // 512 float4
            int k = id >> 4, n4 = id & 15;
            *(float4*)&Bs[k][n4 * 4] = *(const float4*)&Bc[(kk + k) * kNcat + c0 + n4 * 4];
        }
        __syncthreads();
        #pragma unroll
        for (int k = 0; k < 32; k++) {
            float a[8], bv[4];
            *(float4*)&a[0] = *(const float4*)&As[k][ty * 8];
            *(float4*)&a[4] = *(const float4*)&As[k][ty * 8 + 4];
            *(float4*)&bv[0] = *(const float4*)&Bs[k][tx * 4];
            #pragma unroll
            for (int ii = 0; ii < 8; ii++)
                #pragma unroll
                for (int jj = 0; jj < 4; jj++)
                    acc[ii][jj] = fmaf(a[ii], bv[jj], acc[ii][jj]);
        }
    }
    if (ct < 8) {
        #pragma unroll
        for (int ii = 0; ii < 8; ii++) {
            int row = r0 + ty * 8 + ii;
            float4 o;
            o.x = fmaxf(acc[ii][0], 0.f); o.y = fmaxf(acc[ii][1], 0.f);
            o.z = fmaxf(acc[ii][2], 0.f); o.w = fmaxf(acc[ii][3], 0.f);
            *(float4*)&XP0[row * kM + c0 + tx * 4] = o;
        }
    } else {
        float4 ab = *(const float4*)&Ab[tx * 4];
        #pragma unroll
        for (int ii = 0; ii < 8; ii++) {
            int row = r0 + ty * 8 + ii;
            float4 o;
            o.x = acc[ii][0] + ab.x; o.y = acc[ii][1] + ab.y;
            o.z = acc[ii][2] + ab.z; o.w = acc[ii][3] + ab.w;
            *(float4*)&Abuf[row * 64 + tx * 4] = o;
        }
    }
}

// ---------------- fused bmid / relu / y / out ----------------
__global__ __launch_bounds__(256) void k_fused(
    const float* __restrict__ XP0, const float* __restrict__ Abuf,
    const float* __restrict__ BwN, const float* __restrict__ Bb,
    const float* __restrict__ CwT, const float* __restrict__ Cb,
    const float* __restrict__ FRw, const float* __restrict__ FRb,
    float* __restrict__ OUT, int t)
{
    __shared__ float Xs[128][64];
    __shared__ float As2[128][16];
    __shared__ float Bs2[64][16];
    __shared__ float red[4][64][33];
    __shared__ float pos[4][64];
    const int tid = threadIdx.x;
    const int b = blockIdx.x;        // 0..127
    const int mh = blockIdx.y;       // 0..1
    const int ml = tid & 63, dg = tid >> 6;

    for (int mt = 0; mt < 4; mt++) {
        const int mbase = mh * 256 + mt * 64;
        __syncthreads();
        #pragma unroll
        for (int it = 0; it < 8; it++) {
            int id = it * 256 + tid;             // 2048 float4
            int d = id >> 4, mq = id & 15;
            *(float4*)&Xs[d][mq * 4] = *(const float4*)&XP0[(d * kB + b) * kM + mbase + mq * 4];
        }
        for (int c = 0; c < kC; c++) {
            __syncthreads();
            #pragma unroll
            for (int it = 0; it < 2; it++) {
                int id = it * 256 + tid;         // 512 float4
                int d = id >> 2, lq = id & 3;
                *(float4*)&As2[d][lq * 4] = *(const float4*)&Abuf[(d * kB + b) * 64 + c * 16 + lq * 4];
            }
            {
                int m2 = tid >> 2, lq = tid & 3; // 256 float4
                *(float4*)&Bs2[m2][lq * 4] = *(const float4*)&BwN[(c * kM + mbase + m2) * 16 + lq * 4];
            }
            __syncthreads();
            const int mg = mbase + ml;
            const float bb = Bb[c * kM + mg];
            float bsr[16];
            #pragma unroll
            for (int l = 0; l < 16; l++) bsr[l] = Bs2[ml][l];
            float yp[32];
            #pragma unroll
            for (int r = 0; r < 32; r++) yp[r] = 0.f;
            #pragma unroll 4
            for (int dd = 0; dd < 32; dd++) {
                int d = dg * 32 + dd;
                float acc = bb + Xs[d][ml];
                #pragma unroll
                for (int l = 0; l < 16; l++) acc = fmaf(As2[d][l], bsr[l], acc);
                float xr = fmaxf(acc, 0.f);
                const float* cw = &CwT[(c * kD + d) * kRD];   // uniform -> scalar loads
                #pragma unroll
                for (int r = 0; r < 32; r++) yp[r] = fmaf(xr, cw[r], yp[r]);
            }
            #pragma unroll
            for (int r = 0; r < 32; r++) red[dg][ml][r] = yp[r];
            __syncthreads();
            float po = 0.f;
            #pragma unroll
            for (int rr = 0; rr < 8; rr++) {
                int r = dg * 8 + rr;
                float tot = red[0][ml][r] + red[1][ml][r] + red[2][ml][r] + red[3][ml][r];
                tot += Cb[c * kRD + r];
                float y = sigmf(tot);
                po = fmaf(y, FRw[(c * kM + mg) * kRD + r], po);
            }
            pos[dg][ml] = po;
            __syncthreads();
            if (tid < 64) {
                int mgo = mbase + tid;
                float o = pos[0][tid] + pos[1][tid] + pos[2][tid] + pos[3][tid]
                          + FRb[c * kM + mgo];
                OUT[((c * kB + b) * kW + t) * kM + mgo] = o;
            }
        }
    }
}

// ---------------- launch ----------------
extern "C" void kernel_launch(void* const* d_in, const int* in_sizes, int n_in,
                              void* d_out, int out_size, void* d_ws, size_t ws_size,
                              hipStream_t stream) {
    const float* x    = (const float*)d_in[0];
    const float* Hini = (const float*)d_in[1];
    const float* G    = (const float*)d_in[2];
    const float* wx0  = (const float*)d_in[3];
    const float* wh0  = (const float*)d_in[4];
    const float* bx0  = (const float*)d_in[5];
    const float* bh0  = (const float*)d_in[6];
    const float* wx1  = (const float*)d_in[7];
    const float* wh1  = (const float*)d_in[8];
    const float* bx1  = (const float*)d_in[9];
    const float* bh1  = (const float*)d_in[10];
    const float* A_v  = (const float*)d_in[11];
    const float* A_g  = (const float*)d_in[12];
    const float* A_b  = (const float*)d_in[13];
    const float* B_v  = (const float*)d_in[14];
    const float* B_g  = (const float*)d_in[15];
    const float* B_b  = (const float*)d_in[16];
    const float* C_v  = (const float*)d_in[17];
    const float* C_g  = (const float*)d_in[18];
    const float* C_b  = (const float*)d_in[19];
    const float* FR_w = (const float*)d_in[20];
    const float* FR_b = (const float*)d_in[21];
    float* out = (float*)d_out;

    float* ws   = (float*)d_ws;
    float* HNT  = ws;                       // 64*65536
    float* XPT  = HNT  + 64 * kNC;          // 128*65536
    float* XP0  = XPT  + 128 * kNC;         // 16384*512
    float* Abuf = XP0  + kR * kM;           // 16384*64
    float* Bcat = Abuf + kR * 64;           // 512*576
    float* gh1T = Bcat + kM * kNcat;        // 192*512
    float* H1T  = gh1T + 192 * kM;          // 64*512
    float* BwN  = H1T  + 64 * kM;           // 2048*16
    float* CwT  = BwN  + 2048 * 16;         // 4*128*32

    k_init_hnt<<<16384, 256, 0, stream>>>(Hini, HNT);
    k_gh1T<<<384, 256, 0, stream>>>(Hini, wh1, bh1, gh1T);
    k_h1T<<<128, 256, 0, stream>>>(Hini, H1T);
    k_copyG<<<1024, 256, 0, stream>>>(G, Bcat);
    k_norm_aw<<<64, 64, 0, stream>>>(A_v, A_g, Bcat);
    k_norm_bw<<<8, 256, 0, stream>>>(B_v, B_g, BwN);
    k_norm_cw<<<128, 64, 0, stream>>>(C_v, C_g, CwT);

    for (int t = 0; t < kW; t++) {
        k_gru<<<256, 256, 0, stream>>>(x, wx0, wh0, bx0, bh0, wx1, bx1,
                                       gh1T, H1T, HNT, XPT, t);
        k_gemm<<<dim3(128, 9), 256, 0, stream>>>(XPT, Bcat, A_b, XP0, Abuf);
        k_fused<<<dim3(128, 2), 256, 0, stream>>>(XP0, Abuf, BwN, B_b, CwT, C_b,
                                                  FR_w, FR_b, out, t);
    }
}

// Round 2
// 29552.744 us; speedup vs baseline: 1.3944x; 1.3944x over previous
//
#include <hip/hip_runtime.h>
#include <hip/hip_bf16.h>

// Problem constants
constexpr int kB  = 128;   // batch
constexpr int kW  = 64;    // time steps
constexpr int kM  = 512;   // "major" dim
constexpr int kH  = 64;    // GRU hidden
constexpr int kC  = 4;
constexpr int kLR = 16;
constexpr int kRD = 32;
constexpr int kD  = 128;   // L*H
constexpr int kNC = kB * kM;      // 65536 cells
constexpr int kR  = kD * kB;      // 16384 GEMM rows
constexpr int kN  = kM + kC * kLR; // 576 GEMM cols (G | Aw^T)

typedef __attribute__((ext_vector_type(8))) short bf16x8;
typedef __attribute__((ext_vector_type(4))) float f32x4;

__device__ __forceinline__ float sigmf(float v) { return 1.f / (1.f + __expf(-v)); }
__device__ __forceinline__ float tanhf2(float v) { float e = __expf(2.f * v); return 1.f - 2.f / (e + 1.f); }

__device__ __forceinline__ void gl_lds16(const void* g, void* s) {
    __builtin_amdgcn_global_load_lds(
        (const __attribute__((address_space(1))) void*)(g),
        (__attribute__((address_space(3))) void*)(s), 16, 0, 0);
}

// ---------------- prologue kernels ----------------

// HNT[j][cell] = H_init[0, m, j]   (cell = b*512 + m)
__global__ void k_init_hnt(const float* __restrict__ Hini, float* __restrict__ HNT) {
    int id = blockIdx.x * 256 + threadIdx.x;          // 64*65536 total
    int cell = id & (kNC - 1);
    int m = cell & (kM - 1);
    HNT[id] = Hini[m * kH + (id >> 16)];
}

// gh1T[k][m] = bh1[k] + sum_j H_init[1,m,j] * wh1[k,j]
__global__ void k_gh1T(const float* __restrict__ Hini, const float* __restrict__ wh1,
                       const float* __restrict__ bh1, float* __restrict__ gh1T) {
    int id = blockIdx.x * 256 + threadIdx.x;          // 192*512
    int k = id >> 9, m = id & (kM - 1);
    float acc = bh1[k];
    #pragma unroll
    for (int j = 0; j < kH; j++)
        acc = fmaf(Hini[(kM + m) * kH + j], wh1[k * kH + j], acc);
    gh1T[id] = acc;
}

// H1T[i][m] = H_init[1, m, i]
__global__ void k_h1T(const float* __restrict__ Hini, float* __restrict__ H1T) {
    int id = blockIdx.x * 256 + threadIdx.x;          // 64*512
    int i = id >> 9, m = id & (kM - 1);
    H1T[id] = Hini[(kM + m) * kH + i];
}

// BT[n][k] = G[k][n] in bf16 for n<512 (GEMM B pre-transposed, k contiguous)
__global__ void k_buildGT(const float* __restrict__ G, __hip_bfloat16* __restrict__ BT) {
    int id = blockIdx.x * 256 + threadIdx.x;          // 512*512
    int n = id >> 9, k = id & (kM - 1);
    BT[n * kM + k] = __float2bfloat16(G[k * kM + n]);
}

// weight-norm A into BT rows 512..575: BT[512+cl][m] = A_g*A_v/||A_v|| (bf16)
__global__ void k_norm_aw(const float* __restrict__ Av, const float* __restrict__ Ag,
                          __hip_bfloat16* __restrict__ BT) {
    int row = blockIdx.x;        // 0..63 = c*16+l
    int lane = threadIdx.x;      // 64
    float v[8]; float s = 0.f;
    #pragma unroll
    for (int q = 0; q < 8; q++) { v[q] = Av[row * kM + q * 64 + lane]; s += v[q] * v[q]; }
    #pragma unroll
    for (int off = 32; off > 0; off >>= 1) s += __shfl_down(s, off);
    s = __shfl(s, 0);
    float scale = Ag[row] / sqrtf(s);
    #pragma unroll
    for (int q = 0; q < 8; q++)
        BT[(kM + row) * kM + q * 64 + lane] = __float2bfloat16(v[q] * scale);
}

// weight-norm B: BwN[c*512+m][l]
__global__ void k_norm_bw(const float* __restrict__ Bv, const float* __restrict__ Bg,
                          float* __restrict__ BwN) {
    int row = blockIdx.x * 256 + threadIdx.x;   // 0..2047
    float v[16]; float s = 0.f;
    #pragma unroll
    for (int l = 0; l < 16; l++) { v[l] = Bv[row * 16 + l]; s += v[l] * v[l]; }
    float scale = Bg[row] / sqrtf(s);
    #pragma unroll
    for (int l = 0; l < 16; l++) BwN[row * 16 + l] = v[l] * scale;
}

// weight-norm C, transposed: CwT[(c*128+d)*32 + r]
__global__ void k_norm_cw(const float* __restrict__ Cv, const float* __restrict__ Cg,
                          float* __restrict__ CwT) {
    int row = blockIdx.x;        // 0..127 = c*32+r
    int lane = threadIdx.x;      // 64
    int c = row >> 5, r = row & 31;
    float v0 = Cv[row * kD + lane], v1 = Cv[row * kD + 64 + lane];
    float s = v0 * v0 + v1 * v1;
    #pragma unroll
    for (int off = 32; off > 0; off >>= 1) s += __shfl_down(s, off);
    s = __shfl(s, 0);
    float scale = Cg[row] / sqrtf(s);
    CwT[(c * kD + lane) * kRD + r] = v0 * scale;
    CwT[(c * kD + 64 + lane) * kRD + r] = v1 * scale;
}

// ---------------- GRU step ----------------
// 128 cells/block, 2 i-groups of 32 gates each -> 512 blocks (2/CU), 8 waves/CU.
__global__ __launch_bounds__(256) void k_gru(
    const float* __restrict__ x, const float* __restrict__ wx0,
    const float* __restrict__ wh0, const float* __restrict__ bx0,
    const float* __restrict__ bh0, const float* __restrict__ wx1,
    const float* __restrict__ bx1, const float* __restrict__ gh1T,
    const float* __restrict__ H1T, float* __restrict__ HNT,
    __hip_bfloat16* __restrict__ XPT, int t)
{
    __shared__ float h1s[64][128];
    const int tid = threadIdx.x;
    const int cl = tid & 127;         // local cell
    const int g  = tid >> 7;          // i-group (wave-uniform)
    const int cell = blockIdx.x * 128 + cl;
    const int b = cell >> 9, m = cell & (kM - 1);

    float hpr[64];
    #pragma unroll
    for (int j = 0; j < 64; j++) hpr[j] = HNT[j * kNC + cell];
    const float xv = x[(b * kW + t) * kM + m];

    // GRU layer 0 — this group's 32 output gates
    #pragma unroll 2
    for (int ii = 0; ii < 32; ii++) {
        const int i = g * 32 + ii;
        float gr  = bh0[i]       + bx0[i]       + xv * wx0[i];
        float gz  = bh0[64 + i]  + bx0[64 + i]  + xv * wx0[64 + i];
        float gnh = bh0[128 + i];
        float gnx = bx0[128 + i] + xv * wx0[128 + i];
        const float* wr = wh0 + i * 64;
        const float* wz = wh0 + (64 + i) * 64;
        const float* wn = wh0 + (128 + i) * 64;
        #pragma unroll
        for (int j = 0; j < 64; j++) {
            float h = hpr[j];
            gr  = fmaf(wr[j], h, gr);
            gz  = fmaf(wz[j], h, gz);
            gnh = fmaf(wn[j], h, gnh);
        }
        float r = sigmf(gr), z = sigmf(gz);
        float n = tanhf2(gnx + r * gnh);
        float hi = HNT[i * kNC + cell];      // dynamic-index read of hpr[i]
        float h1 = n + z * (hi - n);
        h1s[i][cl] = h1;
        XPT[i * kNC + cell] = __float2bfloat16(h1);
    }
    __syncthreads();
    float hv[64];
    #pragma unroll
    for (int j = 0; j < 64; j++) hv[j] = h1s[j][cl];

    // GRU layer 1 (hidden side fixed: gh1T precomputed)
    #pragma unroll 2
    for (int ii = 0; ii < 32; ii++) {
        const int i = g * 32 + ii;
        float gr  = bx1[i]       + gh1T[i * kM + m];
        float gz  = bx1[64 + i]  + gh1T[(64 + i) * kM + m];
        float gnh =                gh1T[(128 + i) * kM + m];
        float gnx = bx1[128 + i];
        const float* wr = wx1 + i * 64;
        const float* wz = wx1 + (64 + i) * 64;
        const float* wn = wx1 + (128 + i) * 64;
        #pragma unroll
        for (int j = 0; j < 64; j++) {
            float h = hv[j];
            gr  = fmaf(wr[j], h, gr);
            gz  = fmaf(wz[j], h, gz);
            gnx = fmaf(wn[j], h, gnx);
        }
        float r = sigmf(gr), z = sigmf(gz);
        float n = tanhf2(gnx + r * gnh);
        float h01 = H1T[i * kM + m];
        float h2 = n + z * (h01 - n);
        XPT[(64 + i) * kNC + cell] = __float2bfloat16(h2);
        HNT[i * kNC + cell] = h2;
    }
}

// ---------------- MFMA GEMM: [16384 x 512]bf16 @ [512 x 576]bf16 ----------------
// A = XPT row-major [r=d*128+b][k=m]; B staged from BT[n][k] (k contiguous).
// cols 0..511 -> relu -> XP0 ; cols 512..575 -> +A_b -> Abuf
__global__ __launch_bounds__(256) void k_gemm(
    const __hip_bfloat16* __restrict__ X, const __hip_bfloat16* __restrict__ BT,
    const float* __restrict__ Ab, float* __restrict__ XP0,
    float* __restrict__ Abuf)
{
    __shared__ __align__(16) short As[128][64];   // [row][k] 16KB
    __shared__ __align__(16) short Bs[64][64];    // [col][k] 8KB
    const int tid = threadIdx.x;
    const int r0 = blockIdx.x * 128;
    const int n0 = blockIdx.y * 64;
    const int wave = tid >> 6, lane = tid & 63;
    const int wm = wave >> 1, wn = wave & 1;      // 2x2 waves, 64x32 tile each
    const int lr = lane & 15, lq = lane >> 4;

    f32x4 acc[4][2] = {};

    for (int kk = 0; kk < 512; kk += 64) {
        __syncthreads();
        // stage A: 128 rows x 8 chunks(16B), XOR chunk-swizzle on global source
        #pragma unroll
        for (int it = 0; it < 4; it++) {
            int cid = it * 256 + tid;
            int row = cid >> 3, c = cid & 7;
            int cg = c ^ (row & 7);
            gl_lds16(X + ((size_t)(r0 + row) * kM + kk + cg * 8), &As[0][0] + cid * 8);
        }
        // stage B: 64 cols x 8 chunks
        #pragma unroll
        for (int it = 0; it < 2; it++) {
            int cid = it * 256 + tid;
            int col = cid >> 3, c = cid & 7;
            int cg = c ^ (col & 7);
            gl_lds16(BT + ((size_t)(n0 + col) * kM + kk + cg * 8), &Bs[0][0] + cid * 8);
        }
        __syncthreads();   // drains vmcnt(0) -> staged data visible
        #pragma unroll
        for (int w2 = 0; w2 < 2; w2++) {
            bf16x8 af[4], bfr[2];
            #pragma unroll
            for (int fi = 0; fi < 4; fi++) {
                int row = wm * 64 + fi * 16 + lr;
                int c = (w2 * 4 + lq) ^ (row & 7);
                af[fi] = *(const bf16x8*)&As[row][c * 8];
            }
            #pragma unroll
            for (int fj = 0; fj < 2; fj++) {
                int col = wn * 32 + fj * 16 + lr;
                int c = (w2 * 4 + lq) ^ (col & 7);
                bfr[fj] = *(const bf16x8*)&Bs[col][c * 8];
            }
            #pragma unroll
            for (int fi = 0; fi < 4; fi++)
                #pragma unroll
                for (int fj = 0; fj < 2; fj++)
                    acc[fi][fj] = __builtin_amdgcn_mfma_f32_16x16x32_bf16(
                        af[fi], bfr[fj], acc[fi][fj], 0, 0, 0);
        }
    }
    // epilogue: C frag mapping col=lane&15, row=(lane>>4)*4+reg
    if (n0 < kM) {
        #pragma unroll
        for (int fi = 0; fi < 4; fi++)
            #pragma unroll
            for (int fj = 0; fj < 2; fj++) {
                int colg = n0 + wn * 32 + fj * 16 + lr;
                #pragma unroll
                for (int r = 0; r < 4; r++) {
                    int rowg = r0 + wm * 64 + fi * 16 + lq * 4 + r;
                    XP0[(size_t)rowg * kM + colg] = fmaxf(acc[fi][fj][r], 0.f);
                }
            }
    } else {
        #pragma unroll
        for (int fi = 0; fi < 4; fi++)
            #pragma unroll
            for (int fj = 0; fj < 2; fj++) {
                int cl = wn * 32 + fj * 16 + lr;
                float ab = Ab[cl];
                #pragma unroll
                for (int r = 0; r < 4; r++) {
                    int rowg = r0 + wm * 64 + fi * 16 + lq * 4 + r;
                    Abuf[(size_t)rowg * 64 + cl] = acc[fi][fj][r] + ab;
                }
            }
    }
}

// ---------------- fused bmid / relu / y / out ----------------
__global__ __launch_bounds__(256) void k_fused(
    const float* __restrict__ XP0, const float* __restrict__ Abuf,
    const float* __restrict__ BwN, const float* __restrict__ Bb,
    const float* __restrict__ CwT, const float* __restrict__ Cb,
    const float* __restrict__ FRw, const float* __restrict__ FRb,
    float* __restrict__ OUT, int t)
{
    __shared__ float Xs[128][64];
    __shared__ float As2[128][16];
    __shared__ float Bs2[64][16];
    __shared__ float red[4][64][33];
    __shared__ float pos[4][64];
    const int tid = threadIdx.x;
    const int b = blockIdx.x;        // 0..127
    const int mh = blockIdx.y;       // 0..1
    const int ml = tid & 63, dg = tid >> 6;

    for (int mt = 0; mt < 4; mt++) {
        const int mbase = mh * 256 + mt * 64;
        __syncthreads();
        #pragma unroll
        for (int it = 0; it < 8; it++) {
            int id = it * 256 + tid;             // 2048 float4
            int d = id >> 4, mq = id & 15;
            *(float4*)&Xs[d][mq * 4] = *(const float4*)&XP0[(d * kB + b) * kM + mbase + mq * 4];
        }
        for (int c = 0; c < kC; c++) {
            __syncthreads();
            #pragma unroll
            for (int it = 0; it < 2; it++) {
                int id = it * 256 + tid;         // 512 float4
                int d = id >> 2, lq = id & 3;
                *(float4*)&As2[d][lq * 4] = *(const float4*)&Abuf[(d * kB + b) * 64 + c * 16 + lq * 4];
            }
            {
                int m2 = tid >> 2, lq = tid & 3; // 256 float4
                *(float4*)&Bs2[m2][lq * 4] = *(const float4*)&BwN[(c * kM + mbase + m2) * 16 + lq * 4];
            }
            __syncthreads();
            const int mg = mbase + ml;
            const float bb = Bb[c * kM + mg];
            float bsr[16];
            #pragma unroll
            for (int l = 0; l < 16; l++) bsr[l] = Bs2[ml][l];
            float yp[32];
            #pragma unroll
            for (int r = 0; r < 32; r++) yp[r] = 0.f;
            #pragma unroll 4
            for (int dd = 0; dd < 32; dd++) {
                int d = dg * 32 + dd;
                float acc = bb + Xs[d][ml];
                #pragma unroll
                for (int l = 0; l < 16; l++) acc = fmaf(As2[d][l], bsr[l], acc);
                float xr = fmaxf(acc, 0.f);
                const float* cw = &CwT[(c * kD + d) * kRD];   // uniform -> scalar loads
                #pragma unroll
                for (int r = 0; r < 32; r++) yp[r] = fmaf(xr, cw[r], yp[r]);
            }
            #pragma unroll
            for (int r = 0; r < 32; r++) red[dg][ml][r] = yp[r];
            __syncthreads();
            float po = 0.f;
            #pragma unroll
            for (int rr = 0; rr < 8; rr++) {
                int r = dg * 8 + rr;
                float tot = red[0][ml][r] + red[1][ml][r] + red[2][ml][r] + red[3][ml][r];
                tot += Cb[c * kRD + r];
                float y = sigmf(tot);
                po = fmaf(y, FRw[(c * kM + mg) * kRD + r], po);
            }
            pos[dg][ml] = po;
            __syncthreads();
            if (tid < 64) {
                int mgo = mbase + tid;
                float o = pos[0][tid] + pos[1][tid] + pos[2][tid] + pos[3][tid]
                          + FRb[c * kM + mgo];
                OUT[((c * kB + b) * kW + t) * kM + mgo] = o;
            }
        }
    }
}

// ---------------- launch ----------------
extern "C" void kernel_launch(void* const* d_in, const int* in_sizes, int n_in,
                              void* d_out, int out_size, void* d_ws, size_t ws_size,
                              hipStream_t stream) {
    const float* x    = (const float*)d_in[0];
    const float* Hini = (const float*)d_in[1];
    const float* G    = (const float*)d_in[2];
    const float* wx0  = (const float*)d_in[3];
    const float* wh0  = (const float*)d_in[4];
    const float* bx0  = (const float*)d_in[5];
    const float* bh0  = (const float*)d_in[6];
    const float* wx1  = (const float*)d_in[7];
    const float* wh1  = (const float*)d_in[8];
    const float* bx1  = (const float*)d_in[9];
    const float* bh1  = (const float*)d_in[10];
    const float* A_v  = (const float*)d_in[11];
    const float* A_g  = (const float*)d_in[12];
    const float* A_b  = (const float*)d_in[13];
    const float* B_v  = (const float*)d_in[14];
    const float* B_g  = (const float*)d_in[15];
    const float* B_b  = (const float*)d_in[16];
    const float* C_v  = (const float*)d_in[17];
    const float* C_g  = (const float*)d_in[18];
    const float* C_b  = (const float*)d_in[19];
    const float* FR_w = (const float*)d_in[20];
    const float* FR_b = (const float*)d_in[21];
    float* out = (float*)d_out;

    char* w = (char*)d_ws;
    float*          HNT  = (float*)w;          w += (size_t)64 * kNC * 4;   // 16MB
    __hip_bfloat16* XPT  = (__hip_bfloat16*)w; w += (size_t)128 * kNC * 2;  // 16MB
    float*          XP0  = (float*)w;          w += (size_t)kR * kM * 4;    // 32MB
    float*          Abuf = (float*)w;          w += (size_t)kR * 64 * 4;    // 4MB
    __hip_bfloat16* BT   = (__hip_bfloat16*)w; w += (size_t)kN * kM * 2;    // 576KB
    float*          gh1T = (float*)w;          w += (size_t)192 * kM * 4;
    float*          H1T  = (float*)w;          w += (size_t)64 * kM * 4;
    float*          BwN  = (float*)w;          w += (size_t)2048 * 16 * 4;
    float*          CwT  = (float*)w;          w += (size_t)kC * kD * kRD * 4;

    k_init_hnt<<<16384, 256, 0, stream>>>(Hini, HNT);
    k_gh1T<<<384, 256, 0, stream>>>(Hini, wh1, bh1, gh1T);
    k_h1T<<<128, 256, 0, stream>>>(Hini, H1T);
    k_buildGT<<<1024, 256, 0, stream>>>(G, BT);
    k_norm_aw<<<64, 64, 0, stream>>>(A_v, A_g, BT);
    k_norm_bw<<<8, 256, 0, stream>>>(B_v, B_g, BwN);
    k_norm_cw<<<128, 64, 0, stream>>>(C_v, C_g, CwT);

    for (int t = 0; t < kW; t++) {
        k_gru<<<512, 256, 0, stream>>>(x, wx0, wh0, bx0, bh0, wx1, bx1,
                                       gh1T, H1T, HNT, XPT, t);
        k_gemm<<<dim3(128, 9), 256, 0, stream>>>(XPT, BT, A_b, XP0, Abuf);
        k_fused<<<dim3(128, 2), 256, 0, stream>>>(XP0, Abuf, BwN, B_b, CwT, C_b,
                                                  FR_w, FR_b, out, t);
    }
}

// Round 3
// 11494.638 us; speedup vs baseline: 3.5851x; 2.5710x over previous
//
#include <hip/hip_runtime.h>
#include <hip/hip_bf16.h>

// Problem constants
constexpr int kB  = 128;   // batch
constexpr int kW  = 64;    // time steps
constexpr int kM  = 512;   // "major" dim
constexpr int kH  = 64;    // GRU hidden
constexpr int kC  = 4;
constexpr int kLR = 16;
constexpr int kRD = 32;
constexpr int kD  = 128;   // L*H
constexpr int kNC = kB * kM;      // 65536 cells
constexpr int kR  = kD * kB;      // 16384 GEMM rows
constexpr int kN  = kM + kC * kLR; // 576 GEMM cols (G | Aw^T)

typedef __attribute__((ext_vector_type(8))) short bf16x8;
typedef __attribute__((ext_vector_type(4))) float f32x4;

__device__ __forceinline__ float sigmf(float v) { return 1.f / (1.f + __expf(-v)); }
__device__ __forceinline__ float tanhf2(float v) { float e = __expf(2.f * v); return 1.f - 2.f / (e + 1.f); }

__device__ __forceinline__ void gl_lds16(const void* g, void* s) {
    __builtin_amdgcn_global_load_lds(
        (const __attribute__((address_space(1))) void*)(g),
        (__attribute__((address_space(3))) void*)(s), 16, 0, 0);
}

// ---------------- prologue kernels ----------------

// HNT[j][cell] = H_init[0, m, j]   (cell = b*512 + m)
__global__ void k_init_hnt(const float* __restrict__ Hini, float* __restrict__ HNT) {
    int id = blockIdx.x * 256 + threadIdx.x;          // 64*65536 total
    int cell = id & (kNC - 1);
    int m = cell & (kM - 1);
    HNT[id] = Hini[m * kH + (id >> 16)];
}

// gh1T[k][m] = bh1[k] + sum_j H_init[1,m,j] * wh1[k,j]
__global__ void k_gh1T(const float* __restrict__ Hini, const float* __restrict__ wh1,
                       const float* __restrict__ bh1, float* __restrict__ gh1T) {
    int id = blockIdx.x * 256 + threadIdx.x;          // 192*512
    int k = id >> 9, m = id & (kM - 1);
    float acc = bh1[k];
    #pragma unroll
    for (int j = 0; j < kH; j++)
        acc = fmaf(Hini[(kM + m) * kH + j], wh1[k * kH + j], acc);
    gh1T[id] = acc;
}

// H1T[i][m] = H_init[1, m, i]
__global__ void k_h1T(const float* __restrict__ Hini, float* __restrict__ H1T) {
    int id = blockIdx.x * 256 + threadIdx.x;          // 64*512
    int i = id >> 9, m = id & (kM - 1);
    H1T[id] = Hini[(kM + m) * kH + i];
}

// BT[n][k] = G[k][n] in bf16 for n<512 (GEMM B pre-transposed, k contiguous)
__global__ void k_buildGT(const float* __restrict__ G, __hip_bfloat16* __restrict__ BT) {
    int id = blockIdx.x * 256 + threadIdx.x;          // 512*512
    int n = id >> 9, k = id & (kM - 1);
    BT[n * kM + k] = __float2bfloat16(G[k * kM + n]);
}

// weight-norm A into BT rows 512..575: BT[512+cl][m] = A_g*A_v/||A_v|| (bf16)
__global__ void k_norm_aw(const float* __restrict__ Av, const float* __restrict__ Ag,
                          __hip_bfloat16* __restrict__ BT) {
    int row = blockIdx.x;        // 0..63 = c*16+l
    int lane = threadIdx.x;      // 64
    float v[8]; float s = 0.f;
    #pragma unroll
    for (int q = 0; q < 8; q++) { v[q] = Av[row * kM + q * 64 + lane]; s += v[q] * v[q]; }
    #pragma unroll
    for (int off = 32; off > 0; off >>= 1) s += __shfl_down(s, off);
    s = __shfl(s, 0);
    float scale = Ag[row] / sqrtf(s);
    #pragma unroll
    for (int q = 0; q < 8; q++)
        BT[(kM + row) * kM + q * 64 + lane] = __float2bfloat16(v[q] * scale);
}

// weight-norm B: BwN[c*512+m][l]
__global__ void k_norm_bw(const float* __restrict__ Bv, const float* __restrict__ Bg,
                          float* __restrict__ BwN) {
    int row = blockIdx.x * 256 + threadIdx.x;   // 0..2047
    float v[16]; float s = 0.f;
    #pragma unroll
    for (int l = 0; l < 16; l++) { v[l] = Bv[row * 16 + l]; s += v[l] * v[l]; }
    float scale = Bg[row] / sqrtf(s);
    #pragma unroll
    for (int l = 0; l < 16; l++) BwN[row * 16 + l] = v[l] * scale;
}

// weight-norm C, transposed: CwT[(c*128+d)*32 + r]
__global__ void k_norm_cw(const float* __restrict__ Cv, const float* __restrict__ Cg,
                          float* __restrict__ CwT) {
    int row = blockIdx.x;        // 0..127 = c*32+r
    int lane = threadIdx.x;      // 64
    int c = row >> 5, r = row & 31;
    float v0 = Cv[row * kD + lane], v1 = Cv[row * kD + 64 + lane];
    float s = v0 * v0 + v1 * v1;
    #pragma unroll
    for (int off = 32; off > 0; off >>= 1) s += __shfl_down(s, off);
    s = __shfl(s, 0);
    float scale = Cg[row] / sqrtf(s);
    CwT[(c * kD + lane) * kRD + r] = v0 * scale;
    CwT[(c * kD + 64 + lane) * kRD + r] = v1 * scale;
}

// ---------------- GRU step ----------------
// 64 cells/block, 4 i-groups of 16 gates -> 1024 blocks, ~4 blocks/CU.
__global__ __launch_bounds__(256) void k_gru(
    const float* __restrict__ x, const float* __restrict__ wx0,
    const float* __restrict__ wh0, const float* __restrict__ bx0,
    const float* __restrict__ bh0, const float* __restrict__ wx1,
    const float* __restrict__ bx1, const float* __restrict__ gh1T,
    const float* __restrict__ H1T, float* __restrict__ HNT,
    __hip_bfloat16* __restrict__ XPT, int t)
{
    __shared__ float h1s[64][64];     // 16KB
    const int tid = threadIdx.x;
    const int cl = tid & 63;          // local cell
    const int gu = __builtin_amdgcn_readfirstlane(tid >> 6);  // wave-uniform group
    const int cell = blockIdx.x * 64 + cl;
    const int b = cell >> 9, m = cell & (kM - 1);

    float hpr[64];
    #pragma unroll
    for (int j = 0; j < 64; j++) hpr[j] = HNT[j * kNC + cell];
    const float xv = x[(b * kW + t) * kM + m];

    // GRU layer 0 — this group's 16 output gates
    #pragma unroll 2
    for (int ii = 0; ii < 16; ii++) {
        const int i = gu * 16 + ii;
        float gr  = bh0[i]       + bx0[i]       + xv * wx0[i];
        float gz  = bh0[64 + i]  + bx0[64 + i]  + xv * wx0[64 + i];
        float gnh = bh0[128 + i];
        float gnx = bx0[128 + i] + xv * wx0[128 + i];
        const float* wr = wh0 + i * 64;
        const float* wz = wh0 + (64 + i) * 64;
        const float* wn = wh0 + (128 + i) * 64;
        #pragma unroll
        for (int j = 0; j < 64; j++) {
            float h = hpr[j];
            gr  = fmaf(wr[j], h, gr);
            gz  = fmaf(wz[j], h, gz);
            gnh = fmaf(wn[j], h, gnh);
        }
        float r = sigmf(gr), z = sigmf(gz);
        float n = tanhf2(gnx + r * gnh);
        float hi = HNT[i * kNC + cell];      // dynamic-index read of hpr[i]
        float h1 = n + z * (hi - n);
        h1s[i][cl] = h1;
        XPT[i * kNC + cell] = __float2bfloat16(h1);
    }
    __syncthreads();
    float hv[64];
    #pragma unroll
    for (int j = 0; j < 64; j++) hv[j] = h1s[j][cl];

    // GRU layer 1 (hidden side fixed: gh1T precomputed)
    #pragma unroll 2
    for (int ii = 0; ii < 16; ii++) {
        const int i = gu * 16 + ii;
        float gr  = bx1[i]       + gh1T[i * kM + m];
        float gz  = bx1[64 + i]  + gh1T[(64 + i) * kM + m];
        float gnh =                gh1T[(128 + i) * kM + m];
        float gnx = bx1[128 + i];
        const float* wr = wx1 + i * 64;
        const float* wz = wx1 + (64 + i) * 64;
        const float* wn = wx1 + (128 + i) * 64;
        #pragma unroll
        for (int j = 0; j < 64; j++) {
            float h = hv[j];
            gr  = fmaf(wr[j], h, gr);
            gz  = fmaf(wz[j], h, gz);
            gnx = fmaf(wn[j], h, gnx);
        }
        float r = sigmf(gr), z = sigmf(gz);
        float n = tanhf2(gnx + r * gnh);
        float h01 = H1T[i * kM + m];
        float h2 = n + z * (h01 - n);
        XPT[(64 + i) * kNC + cell] = __float2bfloat16(h2);
        HNT[i * kNC + cell] = h2;
    }
}

// ---------------- MFMA GEMM: [16384 x 512]bf16 @ [512 x 576]bf16 ----------------
// A = XPT row-major [r=d*128+b][k=m]; B staged from BT[n][k] (k contiguous).
// cols 0..511 -> relu -> XP0h (bf16) ; cols 512..575 -> +A_b -> Abuf (f32)
__global__ __launch_bounds__(256) void k_gemm(
    const __hip_bfloat16* __restrict__ X, const __hip_bfloat16* __restrict__ BT,
    const float* __restrict__ Ab, __hip_bfloat16* __restrict__ XP0h,
    float* __restrict__ Abuf)
{
    __shared__ __align__(16) short As[128][64];   // [row][k] 16KB
    __shared__ __align__(16) short Bs[64][64];    // [col][k] 8KB
    const int tid = threadIdx.x;
    const int r0 = blockIdx.x * 128;
    const int n0 = blockIdx.y * 64;
    const int wave = tid >> 6, lane = tid & 63;
    const int wm = wave >> 1, wn = wave & 1;      // 2x2 waves, 64x32 tile each
    const int lr = lane & 15, lq = lane >> 4;

    f32x4 acc[4][2] = {};

    for (int kk = 0; kk < 512; kk += 64) {
        __syncthreads();
        // stage A: 128 rows x 8 chunks(16B), XOR chunk-swizzle on global source
        #pragma unroll
        for (int it = 0; it < 4; it++) {
            int cid = it * 256 + tid;
            int row = cid >> 3, c = cid & 7;
            int cg = c ^ (row & 7);
            gl_lds16(X + ((size_t)(r0 + row) * kM + kk + cg * 8), &As[0][0] + cid * 8);
        }
        // stage B: 64 cols x 8 chunks
        #pragma unroll
        for (int it = 0; it < 2; it++) {
            int cid = it * 256 + tid;
            int col = cid >> 3, c = cid & 7;
            int cg = c ^ (col & 7);
            gl_lds16(BT + ((size_t)(n0 + col) * kM + kk + cg * 8), &Bs[0][0] + cid * 8);
        }
        __syncthreads();   // drains vmcnt(0) -> staged data visible
        #pragma unroll
        for (int w2 = 0; w2 < 2; w2++) {
            bf16x8 af[4], bfr[2];
            #pragma unroll
            for (int fi = 0; fi < 4; fi++) {
                int row = wm * 64 + fi * 16 + lr;
                int c = (w2 * 4 + lq) ^ (row & 7);
                af[fi] = *(const bf16x8*)&As[row][c * 8];
            }
            #pragma unroll
            for (int fj = 0; fj < 2; fj++) {
                int col = wn * 32 + fj * 16 + lr;
                int c = (w2 * 4 + lq) ^ (col & 7);
                bfr[fj] = *(const bf16x8*)&Bs[col][c * 8];
            }
            #pragma unroll
            for (int fi = 0; fi < 4; fi++)
                #pragma unroll
                for (int fj = 0; fj < 2; fj++)
                    acc[fi][fj] = __builtin_amdgcn_mfma_f32_16x16x32_bf16(
                        af[fi], bfr[fj], acc[fi][fj], 0, 0, 0);
        }
    }
    // epilogue: C frag mapping col=lane&15, row=(lane>>4)*4+reg
    if (n0 < kM) {
        #pragma unroll
        for (int fi = 0; fi < 4; fi++)
            #pragma unroll
            for (int fj = 0; fj < 2; fj++) {
                int colg = n0 + wn * 32 + fj * 16 + lr;
                #pragma unroll
                for (int r = 0; r < 4; r++) {
                    int rowg = r0 + wm * 64 + fi * 16 + lq * 4 + r;
                    XP0h[(size_t)rowg * kM + colg] = __float2bfloat16(fmaxf(acc[fi][fj][r], 0.f));
                }
            }
    } else {
        #pragma unroll
        for (int fi = 0; fi < 4; fi++)
            #pragma unroll
            for (int fj = 0; fj < 2; fj++) {
                int cl = wn * 32 + fj * 16 + lr;
                float ab = Ab[cl];
                #pragma unroll
                for (int r = 0; r < 4; r++) {
                    int rowg = r0 + wm * 64 + fi * 16 + lq * 4 + r;
                    Abuf[(size_t)rowg * 64 + cl] = acc[fi][fj][r] + ab;
                }
            }
    }
}

// ---------------- fused bmid / relu / y / out ----------------
// One block per (b, c, m-tile of 128). 256 threads = 2 d-groups x 128 m.
__global__ __launch_bounds__(256) void k_fused(
    const __hip_bfloat16* __restrict__ XP0h, const float* __restrict__ Abuf,
    const float* __restrict__ BwN, const float* __restrict__ Bb,
    const float* __restrict__ CwT, const float* __restrict__ Cb,
    const float* __restrict__ FRw, const float* __restrict__ FRb,
    float* __restrict__ OUT, int t)
{
    __shared__ __align__(16) short Xs[128][128];   // bf16 [d][m] 32KB
    __shared__ __align__(16) float As2[128][16];   // 8KB
    __shared__ float red[2][128][33];              // 33.8KB
    __shared__ float pos[2][128];                  // 1KB
    const int tid = threadIdx.x;
    const int b = blockIdx.x;          // 0..127
    const int cz = blockIdx.y;         // 0..15
    const int c = cz >> 2, mt = cz & 3;
    const int mbase = mt * 128;
    const int ml = tid & 127;
    const int dgu = __builtin_amdgcn_readfirstlane(tid >> 7);  // wave-uniform d-group

    // stage Xs (x_p0 tile, bf16) and As2 (a tile, f32)
    #pragma unroll
    for (int it = 0; it < 8; it++) {
        int id = it * 256 + tid;                   // 2048 x 8bf16
        int d = id >> 4, mq = id & 15;
        *(float4*)&Xs[d][mq * 8] =
            *(const float4*)&XP0h[((size_t)d * kB + b) * kM + mbase + mq * 8];
    }
    #pragma unroll
    for (int it = 0; it < 2; it++) {
        int id = it * 256 + tid;                   // 512 float4
        int d = id >> 2, lq = id & 3;
        *(float4*)&As2[d][lq * 4] =
            *(const float4*)&Abuf[((size_t)d * kB + b) * 64 + c * 16 + lq * 4];
    }
    __syncthreads();

    const int mg = mbase + ml;
    const float bb = Bb[c * kM + mg];
    float bsr[16];
    #pragma unroll
    for (int q = 0; q < 4; q++)
        *(float4*)&bsr[q * 4] = *(const float4*)&BwN[((size_t)c * kM + mg) * 16 + q * 4];

    float yp[32];
    #pragma unroll
    for (int r = 0; r < 32; r++) yp[r] = 0.f;

    const float* cwg = &CwT[((size_t)c * kD + dgu * 64) * kRD];  // scalar base
    const __hip_bfloat16* xrow = (const __hip_bfloat16*)&Xs[dgu * 64][0];

    #pragma unroll 4
    for (int dd = 0; dd < 64; dd++) {
        float acc = bb + __bfloat162float(xrow[dd * 128 + ml]);
        #pragma unroll
        for (int q = 0; q < 4; q++) {
            float4 a4 = *(const float4*)&As2[dgu * 64 + dd][q * 4];
            acc = fmaf(a4.x, bsr[q * 4 + 0], acc);
            acc = fmaf(a4.y, bsr[q * 4 + 1], acc);
            acc = fmaf(a4.z, bsr[q * 4 + 2], acc);
            acc = fmaf(a4.w, bsr[q * 4 + 3], acc);
        }
        float xr = fmaxf(acc, 0.f);
        const float* cw = cwg + dd * kRD;
        #pragma unroll
        for (int r = 0; r < 32; r++) yp[r] = fmaf(xr, cw[r], yp[r]);
    }
    #pragma unroll
    for (int r = 0; r < 32; r++) red[dgu][ml][r] = yp[r];
    __syncthreads();

    // tail: y = sigmoid(.) ; out = y @ FRw
    {
        int mlt = tid & 127, rh = tid >> 7;
        float po = 0.f;
        #pragma unroll
        for (int rr = 0; rr < 16; rr++) {
            int r = rh * 16 + rr;
            float tot = red[0][mlt][r] + red[1][mlt][r] + Cb[c * kRD + r];
            float y = sigmf(tot);
            po = fmaf(y, FRw[((size_t)c * kM + mbase + mlt) * kRD + r], po);
        }
        pos[rh][mlt] = po;
    }
    __syncthreads();
    if (tid < 128) {
        int mgo = mbase + tid;
        OUT[((size_t)(c * kB + b) * kW + t) * kM + mgo] =
            pos[0][tid] + pos[1][tid] + FRb[c * kM + mgo];
    }
}

// ---------------- launch ----------------
extern "C" void kernel_launch(void* const* d_in, const int* in_sizes, int n_in,
                              void* d_out, int out_size, void* d_ws, size_t ws_size,
                              hipStream_t stream) {
    const float* x    = (const float*)d_in[0];
    const float* Hini = (const float*)d_in[1];
    const float* G    = (const float*)d_in[2];
    const float* wx0  = (const float*)d_in[3];
    const float* wh0  = (const float*)d_in[4];
    const float* bx0  = (const float*)d_in[5];
    const float* bh0  = (const float*)d_in[6];
    const float* wx1  = (const float*)d_in[7];
    const float* wh1  = (const float*)d_in[8];
    const float* bx1  = (const float*)d_in[9];
    const float* bh1  = (const float*)d_in[10];
    const float* A_v  = (const float*)d_in[11];
    const float* A_g  = (const float*)d_in[12];
    const float* A_b  = (const float*)d_in[13];
    const float* B_v  = (const float*)d_in[14];
    const float* B_g  = (const float*)d_in[15];
    const float* B_b  = (const float*)d_in[16];
    const float* C_v  = (const float*)d_in[17];
    const float* C_g  = (const float*)d_in[18];
    const float* C_b  = (const float*)d_in[19];
    const float* FR_w = (const float*)d_in[20];
    const float* FR_b = (const float*)d_in[21];
    float* out = (float*)d_out;

    char* w = (char*)d_ws;
    float*          HNT  = (float*)w;          w += (size_t)64 * kNC * 4;   // 16MB
    __hip_bfloat16* XPT  = (__hip_bfloat16*)w; w += (size_t)128 * kNC * 2;  // 16MB
    __hip_bfloat16* XP0h = (__hip_bfloat16*)w; w += (size_t)kR * kM * 2;    // 16MB
    float*          Abuf = (float*)w;          w += (size_t)kR * 64 * 4;    // 4MB
    __hip_bfloat16* BT   = (__hip_bfloat16*)w; w += (size_t)kN * kM * 2;    // 576KB
    float*          gh1T = (float*)w;          w += (size_t)192 * kM * 4;
    float*          H1T  = (float*)w;          w += (size_t)64 * kM * 4;
    float*          BwN  = (float*)w;          w += (size_t)2048 * 16 * 4;
    float*          CwT  = (float*)w;          w += (size_t)kC * kD * kRD * 4;

    k_init_hnt<<<16384, 256, 0, stream>>>(Hini, HNT);
    k_gh1T<<<384, 256, 0, stream>>>(Hini, wh1, bh1, gh1T);
    k_h1T<<<128, 256, 0, stream>>>(Hini, H1T);
    k_buildGT<<<1024, 256, 0, stream>>>(G, BT);
    k_norm_aw<<<64, 64, 0, stream>>>(A_v, A_g, BT);
    k_norm_bw<<<8, 256, 0, stream>>>(B_v, B_g, BwN);
    k_norm_cw<<<128, 64, 0, stream>>>(C_v, C_g, CwT);

    for (int t = 0; t < kW; t++) {
        k_gru<<<1024, 256, 0, stream>>>(x, wx0, wh0, bx0, bh0, wx1, bx1,
                                        gh1T, H1T, HNT, XPT, t);
        k_gemm<<<dim3(128, 9), 256, 0, stream>>>(XPT, BT, A_b, XP0h, Abuf);
        k_fused<<<dim3(128, 16), 256, 0, stream>>>(XP0h, Abuf, BwN, B_b, CwT, C_b,
                                                   FR_w, FR_b, out, t);
    }
}

// Round 4
// 8377.320 us; speedup vs baseline: 4.9191x; 1.3721x over previous
//
#include <hip/hip_runtime.h>
#include <hip/hip_bf16.h>

// Problem constants
constexpr int kB  = 128;   // batch
constexpr int kW  = 64;    // time steps
constexpr int kM  = 512;   // "major" dim
constexpr int kH  = 64;    // GRU hidden
constexpr int kC  = 4;
constexpr int kLR = 16;
constexpr int kRD = 32;
constexpr int kD  = 128;   // L*H
constexpr int kNC = kB * kM;      // 65536 cells
constexpr int kR  = kD * kB;      // 16384 GEMM rows
constexpr int kN  = kM + kC * kLR; // 576 GEMM cols (G | Aw^T)

typedef __attribute__((ext_vector_type(8))) short bf16x8;
typedef __attribute__((ext_vector_type(4))) float f32x4;

__device__ __forceinline__ float sigmf(float v) { return 1.f / (1.f + __expf(-v)); }
__device__ __forceinline__ float tanhf2(float v) { float e = __expf(2.f * v); return 1.f - 2.f / (e + 1.f); }

__device__ __forceinline__ unsigned short f2bfu(float f) {
    union { __hip_bfloat16 h; unsigned short u; } cv; cv.h = __float2bfloat16(f); return cv.u;
}

__device__ __forceinline__ void gl_lds16(const void* g, void* s) {
    __builtin_amdgcn_global_load_lds(
        (const __attribute__((address_space(1))) void*)(g),
        (__attribute__((address_space(3))) void*)(s), 16, 0, 0);
}

// ---------------- prologue kernels ----------------

// HNT[j][cell] = H_init[0, m, j]   (cell = b*512 + m)
__global__ void k_init_hnt(const float* __restrict__ Hini, float* __restrict__ HNT) {
    int id = blockIdx.x * 256 + threadIdx.x;          // 64*65536 total
    int cell = id & (kNC - 1);
    int m = cell & (kM - 1);
    HNT[id] = Hini[m * kH + (id >> 16)];
}

// gh1T[k][m] = bh1[k] + sum_j H_init[1,m,j] * wh1[k,j]
__global__ void k_gh1T(const float* __restrict__ Hini, const float* __restrict__ wh1,
                       const float* __restrict__ bh1, float* __restrict__ gh1T) {
    int id = blockIdx.x * 256 + threadIdx.x;          // 192*512
    int k = id >> 9, m = id & (kM - 1);
    float acc = bh1[k];
    #pragma unroll
    for (int j = 0; j < kH; j++)
        acc = fmaf(Hini[(kM + m) * kH + j], wh1[k * kH + j], acc);
    gh1T[id] = acc;
}

// H1T[i][m] = H_init[1, m, i]
__global__ void k_h1T(const float* __restrict__ Hini, float* __restrict__ H1T) {
    int id = blockIdx.x * 256 + threadIdx.x;          // 64*512
    int i = id >> 9, m = id & (kM - 1);
    H1T[id] = Hini[(kM + m) * kH + i];
}

// BT[n][k] = G[k][n] in bf16 for n<512 (GEMM B pre-transposed, k contiguous)
__global__ void k_buildGT(const float* __restrict__ G, __hip_bfloat16* __restrict__ BT) {
    int id = blockIdx.x * 256 + threadIdx.x;          // 512*512
    int n = id >> 9, k = id & (kM - 1);
    BT[n * kM + k] = __float2bfloat16(G[k * kM + n]);
}

// weight-norm A into BT rows 512..575: BT[512+cl][m] = A_g*A_v/||A_v|| (bf16)
__global__ void k_norm_aw(const float* __restrict__ Av, const float* __restrict__ Ag,
                          __hip_bfloat16* __restrict__ BT) {
    int row = blockIdx.x;        // 0..63 = c*16+l
    int lane = threadIdx.x;      // 64
    float v[8]; float s = 0.f;
    #pragma unroll
    for (int q = 0; q < 8; q++) { v[q] = Av[row * kM + q * 64 + lane]; s += v[q] * v[q]; }
    #pragma unroll
    for (int off = 32; off > 0; off >>= 1) s += __shfl_down(s, off);
    s = __shfl(s, 0);
    float scale = Ag[row] / sqrtf(s);
    #pragma unroll
    for (int q = 0; q < 8; q++)
        BT[(kM + row) * kM + q * 64 + lane] = __float2bfloat16(v[q] * scale);
}

// weight-norm B -> bf16 [c*512+m][32]: l<16 = Bw, l==16 = B_b, rest 0
__global__ void k_norm_bw(const float* __restrict__ Bv, const float* __restrict__ Bg,
                          const float* __restrict__ Bb, __hip_bfloat16* __restrict__ BwNh) {
    int row = blockIdx.x * 256 + threadIdx.x;   // 0..2047 = c*512+m
    float v[16]; float s = 0.f;
    #pragma unroll
    for (int l = 0; l < 16; l++) { v[l] = Bv[row * 16 + l]; s += v[l] * v[l]; }
    float scale = Bg[row] / sqrtf(s);
    #pragma unroll
    for (int l = 0; l < 16; l++) BwNh[row * 32 + l] = __float2bfloat16(v[l] * scale);
    BwNh[row * 32 + 16] = __float2bfloat16(Bb[row]);
    #pragma unroll
    for (int l = 17; l < 32; l++) BwNh[row * 32 + l] = __float2bfloat16(0.f);
}

// weight-norm C -> bf16 [c*32+r][128 d] (natural C_v layout)
__global__ void k_norm_cw(const float* __restrict__ Cv, const float* __restrict__ Cg,
                          __hip_bfloat16* __restrict__ CwB) {
    int row = blockIdx.x;        // 0..127 = c*32+r
    int lane = threadIdx.x;      // 64
    float v0 = Cv[row * kD + lane], v1 = Cv[row * kD + 64 + lane];
    float s = v0 * v0 + v1 * v1;
    #pragma unroll
    for (int off = 32; off > 0; off >>= 1) s += __shfl_down(s, off);
    s = __shfl(s, 0);
    float scale = Cg[row] / sqrtf(s);
    CwB[row * kD + lane] = __float2bfloat16(v0 * scale);
    CwB[row * kD + 64 + lane] = __float2bfloat16(v1 * scale);
}

// ---------------- GRU step ----------------
// 64 cells/block, 4 i-groups of 16 gates -> 1024 blocks, ~4 blocks/CU.
__global__ __launch_bounds__(256) void k_gru(
    const float* __restrict__ x, const float* __restrict__ wx0,
    const float* __restrict__ wh0, const float* __restrict__ bx0,
    const float* __restrict__ bh0, const float* __restrict__ wx1,
    const float* __restrict__ bx1, const float* __restrict__ gh1T,
    const float* __restrict__ H1T, float* __restrict__ HNT,
    __hip_bfloat16* __restrict__ XPT, int t)
{
    __shared__ float h1s[64][64];     // 16KB
    const int tid = threadIdx.x;
    const int cl = tid & 63;          // local cell
    const int gu = __builtin_amdgcn_readfirstlane(tid >> 6);  // wave-uniform group
    const int cell = blockIdx.x * 64 + cl;
    const int b = cell >> 9, m = cell & (kM - 1);

    float hpr[64];
    #pragma unroll
    for (int j = 0; j < 64; j++) hpr[j] = HNT[j * kNC + cell];
    const float xv = x[(b * kW + t) * kM + m];

    // GRU layer 0 — this group's 16 output gates
    #pragma unroll 2
    for (int ii = 0; ii < 16; ii++) {
        const int i = gu * 16 + ii;
        float gr  = bh0[i]       + bx0[i]       + xv * wx0[i];
        float gz  = bh0[64 + i]  + bx0[64 + i]  + xv * wx0[64 + i];
        float gnh = bh0[128 + i];
        float gnx = bx0[128 + i] + xv * wx0[128 + i];
        const float* wr = wh0 + i * 64;
        const float* wz = wh0 + (64 + i) * 64;
        const float* wn = wh0 + (128 + i) * 64;
        #pragma unroll
        for (int j = 0; j < 64; j++) {
            float h = hpr[j];
            gr  = fmaf(wr[j], h, gr);
            gz  = fmaf(wz[j], h, gz);
            gnh = fmaf(wn[j], h, gnh);
        }
        float r = sigmf(gr), z = sigmf(gz);
        float n = tanhf2(gnx + r * gnh);
        float hi = HNT[i * kNC + cell];      // dynamic-index read of hpr[i]
        float h1 = n + z * (hi - n);
        h1s[i][cl] = h1;
        XPT[i * kNC + cell] = __float2bfloat16(h1);
    }
    __syncthreads();
    float hv[64];
    #pragma unroll
    for (int j = 0; j < 64; j++) hv[j] = h1s[j][cl];

    // GRU layer 1 (hidden side fixed: gh1T precomputed)
    #pragma unroll 2
    for (int ii = 0; ii < 16; ii++) {
        const int i = gu * 16 + ii;
        float gr  = bx1[i]       + gh1T[i * kM + m];
        float gz  = bx1[64 + i]  + gh1T[(64 + i) * kM + m];
        float gnh =                gh1T[(128 + i) * kM + m];
        float gnx = bx1[128 + i];
        const float* wr = wx1 + i * 64;
        const float* wz = wx1 + (64 + i) * 64;
        const float* wn = wx1 + (128 + i) * 64;
        #pragma unroll
        for (int j = 0; j < 64; j++) {
            float h = hv[j];
            gr  = fmaf(wr[j], h, gr);
            gz  = fmaf(wz[j], h, gz);
            gnx = fmaf(wn[j], h, gnx);
        }
        float r = sigmf(gr), z = sigmf(gz);
        float n = tanhf2(gnx + r * gnh);
        float h01 = H1T[i * kM + m];
        float h2 = n + z * (h01 - n);
        XPT[(64 + i) * kNC + cell] = __float2bfloat16(h2);
        HNT[i * kNC + cell] = h2;
    }
}

// ---------------- MFMA GEMM: [16384 x 512]bf16 @ [512 x 576]bf16 ----------------
__global__ __launch_bounds__(256) void k_gemm(
    const __hip_bfloat16* __restrict__ X, const __hip_bfloat16* __restrict__ BT,
    const float* __restrict__ Ab, __hip_bfloat16* __restrict__ XP0h,
    float* __restrict__ Abuf)
{
    __shared__ __align__(16) short As[128][64];   // [row][k] 16KB
    __shared__ __align__(16) short Bs[64][64];    // [col][k] 8KB
    const int tid = threadIdx.x;
    const int r0 = blockIdx.x * 128;
    const int n0 = blockIdx.y * 64;
    const int wave = tid >> 6, lane = tid & 63;
    const int wm = wave >> 1, wn = wave & 1;      // 2x2 waves, 64x32 tile each
    const int lr = lane & 15, lq = lane >> 4;

    f32x4 acc[4][2] = {};

    for (int kk = 0; kk < 512; kk += 64) {
        __syncthreads();
        #pragma unroll
        for (int it = 0; it < 4; it++) {
            int cid = it * 256 + tid;
            int row = cid >> 3, c = cid & 7;
            int cg = c ^ (row & 7);
            gl_lds16(X + ((size_t)(r0 + row) * kM + kk + cg * 8), &As[0][0] + cid * 8);
        }
        #pragma unroll
        for (int it = 0; it < 2; it++) {
            int cid = it * 256 + tid;
            int col = cid >> 3, c = cid & 7;
            int cg = c ^ (col & 7);
            gl_lds16(BT + ((size_t)(n0 + col) * kM + kk + cg * 8), &Bs[0][0] + cid * 8);
        }
        __syncthreads();   // drains vmcnt(0) -> staged data visible
        #pragma unroll
        for (int w2 = 0; w2 < 2; w2++) {
            bf16x8 af[4], bfr[2];
            #pragma unroll
            for (int fi = 0; fi < 4; fi++) {
                int row = wm * 64 + fi * 16 + lr;
                int c = (w2 * 4 + lq) ^ (row & 7);
                af[fi] = *(const bf16x8*)&As[row][c * 8];
            }
            #pragma unroll
            for (int fj = 0; fj < 2; fj++) {
                int col = wn * 32 + fj * 16 + lr;
                int c = (w2 * 4 + lq) ^ (col & 7);
                bfr[fj] = *(const bf16x8*)&Bs[col][c * 8];
            }
            #pragma unroll
            for (int fi = 0; fi < 4; fi++)
                #pragma unroll
                for (int fj = 0; fj < 2; fj++)
                    acc[fi][fj] = __builtin_amdgcn_mfma_f32_16x16x32_bf16(
                        af[fi], bfr[fj], acc[fi][fj], 0, 0, 0);
        }
    }
    if (n0 < kM) {
        #pragma unroll
        for (int fi = 0; fi < 4; fi++)
            #pragma unroll
            for (int fj = 0; fj < 2; fj++) {
                int colg = n0 + wn * 32 + fj * 16 + lr;
                #pragma unroll
                for (int r = 0; r < 4; r++) {
                    int rowg = r0 + wm * 64 + fi * 16 + lq * 4 + r;
                    XP0h[(size_t)rowg * kM + colg] = __float2bfloat16(fmaxf(acc[fi][fj][r], 0.f));
                }
            }
    } else {
        #pragma unroll
        for (int fi = 0; fi < 4; fi++)
            #pragma unroll
            for (int fj = 0; fj < 2; fj++) {
                int cl = wn * 32 + fj * 16 + lr;
                float ab = Ab[cl];
                #pragma unroll
                for (int r = 0; r < 4; r++) {
                    int rowg = r0 + wm * 64 + fi * 16 + lq * 4 + r;
                    Abuf[(size_t)rowg * 64 + cl] = acc[fi][fj][r] + ab;
                }
            }
    }
}

// ---------------- fused bmid / relu / y / out (MFMA) ----------------
// Block = (b, c, m-half of 256). 4 waves; wave w owns 64 m (2 subs of 32).
// Stage 1: bmid[d,m] = a[d,16]@Bw[16,m] (K padded to 32, bias as unit column)
//          + x_p0, relu -> bf16 -> wave-private LDS Xr[m][d] (XOR-swizzled)
// Stage 2: y[m,r] = Xr[m,:]@Cw[r,:] (K=128) -> sigmoid -> FR dot -> out
__global__ __launch_bounds__(256) void k_fused(
    const __hip_bfloat16* __restrict__ XP0h, const float* __restrict__ Abuf,
    const __hip_bfloat16* __restrict__ BwNh, const __hip_bfloat16* __restrict__ CwB,
    const float* __restrict__ Cb, const float* __restrict__ FRw,
    const float* __restrict__ FRb, float* __restrict__ OUT, int t)
{
    __shared__ __align__(16) short CwS[32][136];     // 8.5KB, pad-8 rows
    __shared__ __align__(16) short Xr[4][32][128];   // 32KB, per-wave [m][d] bf16
    const int tid = threadIdx.x;
    const int b = blockIdx.x;
    const int c = blockIdx.y >> 1, mh = blockIdx.y & 1;
    const int w = tid >> 6, lane = tid & 63;
    const int lr = lane & 15, lq = lane >> 4;

    // stage Cw tile [32 r][128 d]
    #pragma unroll
    for (int it = 0; it < 2; it++) {
        int cid = it * 256 + tid;                    // 512 chunks of 8 bf16
        int r = cid >> 4, ch = cid & 15;
        *(float4*)&CwS[r][ch * 8] =
            *(const float4*)&CwB[((size_t)c * kRD + r) * kD + ch * 8];
    }

    // persistent A-frags for stage 1: af[dt], row d = dt*16+lr, k = l (padded 32)
    bf16x8 af[8];
    #pragma unroll
    for (int dt = 0; dt < 8; dt++) {
        bf16x8 v = {};
        if (lq < 2) {
            const float* ap = &Abuf[((size_t)(dt * 16 + lr) * kB + b) * 64 + c * 16 + lq * 8];
            float4 a0 = *(const float4*)ap;
            float4 a1 = *(const float4*)(ap + 4);
            v[0] = (short)f2bfu(a0.x); v[1] = (short)f2bfu(a0.y);
            v[2] = (short)f2bfu(a0.z); v[3] = (short)f2bfu(a0.w);
            v[4] = (short)f2bfu(a1.x); v[5] = (short)f2bfu(a1.y);
            v[6] = (short)f2bfu(a1.z); v[7] = (short)f2bfu(a1.w);
        } else if (lq == 2) {
            v[0] = (short)0x3F80;     // 1.0 at l=16 -> bias column
        }
        af[dt] = v;
    }
    __syncthreads();

    // persistent B-frags for stage 2: cwf[rt][s], row r = rt*16+lr, k d = s*32+lq*8
    bf16x8 cwf[2][4];
    #pragma unroll
    for (int rt = 0; rt < 2; rt++)
        #pragma unroll
        for (int s = 0; s < 4; s++)
            cwf[rt][s] = *(const bf16x8*)&CwS[rt * 16 + lr][s * 32 + lq * 8];

    const float cbv0 = Cb[c * kRD + lr];
    const float cbv1 = Cb[c * kRD + 16 + lr];
    const int mw0 = mh * 256 + w * 64;

    for (int ms = 0; ms < 2; ms++) {
        const int mbase = mw0 + ms * 32;
        // ---- stage 1 ----
        #pragma unroll
        for (int mt2 = 0; mt2 < 2; mt2++) {
            const int mg = mbase + mt2 * 16 + lr;    // D col = m
            const int mloc = mt2 * 16 + lr;
            bf16x8 bf1 = *(const bf16x8*)&BwNh[((size_t)c * kM + mg) * 32 + lq * 8];
            f32x4 acc1[8] = {};
            #pragma unroll
            for (int dt = 0; dt < 8; dt++)
                acc1[dt] = __builtin_amdgcn_mfma_f32_16x16x32_bf16(af[dt], bf1, acc1[dt], 0, 0, 0);
            // + x_p0, relu, pack bf16, swizzled LDS write (wave-private)
            #pragma unroll
            for (int dt = 0; dt < 8; dt++) {
                const int d0 = dt * 16 + lq * 4;     // D row = d
                float v0 = acc1[dt][0] + __bfloat162float(XP0h[((size_t)(d0 + 0) * kB + b) * kM + mg]);
                float v1 = acc1[dt][1] + __bfloat162float(XP0h[((size_t)(d0 + 1) * kB + b) * kM + mg]);
                float v2 = acc1[dt][2] + __bfloat162float(XP0h[((size_t)(d0 + 2) * kB + b) * kM + mg]);
                float v3 = acc1[dt][3] + __bfloat162float(XP0h[((size_t)(d0 + 3) * kB + b) * kM + mg]);
                unsigned int lo = (unsigned int)f2bfu(fmaxf(v0, 0.f)) |
                                  ((unsigned int)f2bfu(fmaxf(v1, 0.f)) << 16);
                unsigned int hi = (unsigned int)f2bfu(fmaxf(v2, 0.f)) |
                                  ((unsigned int)f2bfu(fmaxf(v3, 0.f)) << 16);
                const int c16 = dt * 2 + (lq >> 1), half = lq & 1;
                const int col = ((c16 ^ (mloc & 7)) * 8) + half * 4;   // in shorts
                uint2 pk; pk.x = lo; pk.y = hi;
                *(uint2*)&Xr[w][mloc][col] = pk;
            }
        }
        // ---- stage 2 ----
        #pragma unroll
        for (int mt2 = 0; mt2 < 2; mt2++) {
            const int mloc = mt2 * 16 + lr;          // A row = m
            bf16x8 xa[4];
            #pragma unroll
            for (int s = 0; s < 4; s++) {
                const int c16 = s * 4 + lq;
                xa[s] = *(const bf16x8*)&Xr[w][mloc][(c16 ^ (mloc & 7)) * 8];
            }
            float po0 = 0.f, po1 = 0.f, po2 = 0.f, po3 = 0.f;
            #pragma unroll
            for (int rt = 0; rt < 2; rt++) {
                f32x4 a2 = {};
                #pragma unroll
                for (int s = 0; s < 4; s++)
                    a2 = __builtin_amdgcn_mfma_f32_16x16x32_bf16(xa[s], cwf[rt][s], a2, 0, 0, 0);
                const float cb = rt ? cbv1 : cbv0;
                const int r = rt * 16 + lr;          // D col = r
                const int mrow = mbase + mt2 * 16 + lq * 4;  // D row = m
                po0 = fmaf(sigmf(a2[0] + cb), FRw[((size_t)c * kM + mrow + 0) * kRD + r], po0);
                po1 = fmaf(sigmf(a2[1] + cb), FRw[((size_t)c * kM + mrow + 1) * kRD + r], po1);
                po2 = fmaf(sigmf(a2[2] + cb), FRw[((size_t)c * kM + mrow + 2) * kRD + r], po2);
                po3 = fmaf(sigmf(a2[3] + cb), FRw[((size_t)c * kM + mrow + 3) * kRD + r], po3);
            }
            // reduce over the 16-lane r-group
            #pragma unroll
            for (int off = 8; off > 0; off >>= 1) {
                po0 += __shfl_xor(po0, off);
                po1 += __shfl_xor(po1, off);
                po2 += __shfl_xor(po2, off);
                po3 += __shfl_xor(po3, off);
            }
            if (lr == 0) {
                const int mo = mbase + mt2 * 16 + lq * 4;
                const float* frb = &FRb[c * kM + mo];
                float4 o;
                o.x = po0 + frb[0]; o.y = po1 + frb[1];
                o.z = po2 + frb[2]; o.w = po3 + frb[3];
                *(float4*)&OUT[((size_t)(c * kB + b) * kW + t) * kM + mo] = o;
            }
        }
    }
}

// ---------------- launch ----------------
extern "C" void kernel_launch(void* const* d_in, const int* in_sizes, int n_in,
                              void* d_out, int out_size, void* d_ws, size_t ws_size,
                              hipStream_t stream) {
    const float* x    = (const float*)d_in[0];
    const float* Hini = (const float*)d_in[1];
    const float* G    = (const float*)d_in[2];
    const float* wx0  = (const float*)d_in[3];
    const float* wh0  = (const float*)d_in[4];
    const float* bx0  = (const float*)d_in[5];
    const float* bh0  = (const float*)d_in[6];
    const float* wx1  = (const float*)d_in[7];
    const float* wh1  = (const float*)d_in[8];
    const float* bx1  = (const float*)d_in[9];
    const float* bh1  = (const float*)d_in[10];
    const float* A_v  = (const float*)d_in[11];
    const float* A_g  = (const float*)d_in[12];
    const float* A_b  = (const float*)d_in[13];
    const float* B_v  = (const float*)d_in[14];
    const float* B_g  = (const float*)d_in[15];
    const float* B_b  = (const float*)d_in[16];
    const float* C_v  = (const float*)d_in[17];
    const float* C_g  = (const float*)d_in[18];
    const float* C_b  = (const float*)d_in[19];
    const float* FR_w = (const float*)d_in[20];
    const float* FR_b = (const float*)d_in[21];
    float* out = (float*)d_out;

    char* w = (char*)d_ws;
    float*          HNT  = (float*)w;          w += (size_t)64 * kNC * 4;   // 16MB
    __hip_bfloat16* XPT  = (__hip_bfloat16*)w; w += (size_t)128 * kNC * 2;  // 16MB
    __hip_bfloat16* XP0h = (__hip_bfloat16*)w; w += (size_t)kR * kM * 2;    // 16MB
    float*          Abuf = (float*)w;          w += (size_t)kR * 64 * 4;    // 4MB
    __hip_bfloat16* BT   = (__hip_bfloat16*)w; w += (size_t)kN * kM * 2;    // 576KB
    float*          gh1T = (float*)w;          w += (size_t)192 * kM * 4;
    float*          H1T  = (float*)w;          w += (size_t)64 * kM * 4;
    __hip_bfloat16* BwNh = (__hip_bfloat16*)w; w += (size_t)2048 * 32 * 2;  // 128KB
    __hip_bfloat16* CwB  = (__hip_bfloat16*)w; w += (size_t)kC * kRD * kD * 2; // 32KB

    k_init_hnt<<<16384, 256, 0, stream>>>(Hini, HNT);
    k_gh1T<<<384, 256, 0, stream>>>(Hini, wh1, bh1, gh1T);
    k_h1T<<<128, 256, 0, stream>>>(Hini, H1T);
    k_buildGT<<<1024, 256, 0, stream>>>(G, BT);
    k_norm_aw<<<64, 64, 0, stream>>>(A_v, A_g, BT);
    k_norm_bw<<<8, 256, 0, stream>>>(B_v, B_g, B_b, BwNh);
    k_norm_cw<<<128, 64, 0, stream>>>(C_v, C_g, CwB);

    for (int t = 0; t < kW; t++) {
        k_gru<<<1024, 256, 0, stream>>>(x, wx0, wh0, bx0, bh0, wx1, bx1,
                                        gh1T, H1T, HNT, XPT, t);
        k_gemm<<<dim3(128, 9), 256, 0, stream>>>(XPT, BT, A_b, XP0h, Abuf);
        k_fused<<<dim3(128, 8), 256, 0, stream>>>(XP0h, Abuf, BwNh, CwB,
                                                  C_b, FR_w, FR_b, out, t);
    }
}

// Round 5
// 5157.166 us; speedup vs baseline: 7.9907x; 1.6244x over previous
//
#include <hip/hip_runtime.h>
#include <hip/hip_bf16.h>

// Problem constants
constexpr int kB  = 128;   // batch
constexpr int kW  = 64;    // time steps
constexpr int kM  = 512;   // "major" dim
constexpr int kH  = 64;    // GRU hidden
constexpr int kC  = 4;
constexpr int kLR = 16;
constexpr int kRD = 32;
constexpr int kD  = 128;   // L*H
constexpr int kNC = kB * kM;      // 65536 cells
constexpr int kR  = kD * kB;      // 16384 GEMM rows
constexpr int kN  = kM + kC * kLR; // 576 GEMM cols (G | Aw^T)

typedef __attribute__((ext_vector_type(8))) short bf16x8;
typedef __attribute__((ext_vector_type(4))) float f32x4;

__device__ __forceinline__ float sigmf(float v) { return 1.f / (1.f + __expf(-v)); }
__device__ __forceinline__ float tanhf2(float v) { float e = __expf(2.f * v); return 1.f - 2.f / (e + 1.f); }

__device__ __forceinline__ unsigned short f2bfu(float f) {
    union { __hip_bfloat16 h; unsigned short u; } cv; cv.h = __float2bfloat16(f); return cv.u;
}
__device__ __forceinline__ float bfu2f(unsigned short s) {
    return __uint_as_float(((unsigned)s) << 16);
}

__device__ __forceinline__ void gl_lds16(const void* g, void* s) {
    __builtin_amdgcn_global_load_lds(
        (const __attribute__((address_space(1))) void*)(g),
        (__attribute__((address_space(3))) void*)(s), 16, 0, 0);
}

// swizzled bf16 element read from a [rows][64] bf16 LDS tile staged with chunk^=(row&7)
__device__ __forceinline__ float lds_bf(const short* base, int row, int i) {
    unsigned short s = (unsigned short)base[row * 64 + (((i >> 3) ^ (row & 7)) << 3) + (i & 7)];
    return bfu2f(s);
}

// ---------------- prologue kernels ----------------

// HcG[cell][j] = bf16(H_init[0, m, j])   (cell = b*512 + m)
__global__ void k_initHc(const float* __restrict__ Hini, __hip_bfloat16* __restrict__ HcG) {
    int id = blockIdx.x * 256 + threadIdx.x;          // 65536*64
    int cell = id >> 6, j = id & 63;
    int m = cell & (kM - 1);
    HcG[id] = __float2bfloat16(Hini[m * kH + j]);
}

// H1b[m][j] = bf16(H_init[1, m, j])
__global__ void k_h1b(const float* __restrict__ Hini, __hip_bfloat16* __restrict__ H1b) {
    int id = blockIdx.x * 256 + threadIdx.x;          // 512*64
    H1b[id] = __float2bfloat16(Hini[(kM + (id >> 6)) * kH + (id & 63)]);
}

// W0g[192][64] = bf16(wh0); W1g[192][128] = bf16([wx1 | wh1])
__global__ void k_packW(const float* __restrict__ wh0, const float* __restrict__ wx1,
                        const float* __restrict__ wh1, __hip_bfloat16* __restrict__ W0g,
                        __hip_bfloat16* __restrict__ W1g) {
    int id = blockIdx.x * 256 + threadIdx.x;          // 192*128
    int r = id >> 7, ci = id & 127;
    W1g[id] = __float2bfloat16(ci < 64 ? wx1[r * 64 + ci] : wh1[r * 64 + ci - 64]);
    if (ci < 64) W0g[r * 64 + ci] = __float2bfloat16(wh0[r * 64 + ci]);
}

// BT[n][k] = G[k][n] in bf16 for n<512 (GEMM B pre-transposed, k contiguous)
__global__ void k_buildGT(const float* __restrict__ G, __hip_bfloat16* __restrict__ BT) {
    int id = blockIdx.x * 256 + threadIdx.x;          // 512*512
    int n = id >> 9, k = id & (kM - 1);
    BT[n * kM + k] = __float2bfloat16(G[k * kM + n]);
}

// weight-norm A into BT rows 512..575: BT[512+cl][m] = A_g*A_v/||A_v|| (bf16)
__global__ void k_norm_aw(const float* __restrict__ Av, const float* __restrict__ Ag,
                          __hip_bfloat16* __restrict__ BT) {
    int row = blockIdx.x;        // 0..63 = c*16+l
    int lane = threadIdx.x;      // 64
    float v[8]; float s = 0.f;
    #pragma unroll
    for (int q = 0; q < 8; q++) { v[q] = Av[row * kM + q * 64 + lane]; s += v[q] * v[q]; }
    #pragma unroll
    for (int off = 32; off > 0; off >>= 1) s += __shfl_down(s, off);
    s = __shfl(s, 0);
    float scale = Ag[row] / sqrtf(s);
    #pragma unroll
    for (int q = 0; q < 8; q++)
        BT[(kM + row) * kM + q * 64 + lane] = __float2bfloat16(v[q] * scale);
}

// weight-norm B -> bf16 [c*512+m][32]: l<16 = Bw, l==16 = B_b, rest 0
__global__ void k_norm_bw(const float* __restrict__ Bv, const float* __restrict__ Bg,
                          const float* __restrict__ Bb, __hip_bfloat16* __restrict__ BwNh) {
    int row = blockIdx.x * 256 + threadIdx.x;   // 0..2047 = c*512+m
    float v[16]; float s = 0.f;
    #pragma unroll
    for (int l = 0; l < 16; l++) { v[l] = Bv[row * 16 + l]; s += v[l] * v[l]; }
    float scale = Bg[row] / sqrtf(s);
    #pragma unroll
    for (int l = 0; l < 16; l++) BwNh[row * 32 + l] = __float2bfloat16(v[l] * scale);
    BwNh[row * 32 + 16] = __float2bfloat16(Bb[row]);
    #pragma unroll
    for (int l = 17; l < 32; l++) BwNh[row * 32 + l] = __float2bfloat16(0.f);
}

// weight-norm C -> bf16 [c*32+r][128 d] (natural C_v layout)
__global__ void k_norm_cw(const float* __restrict__ Cv, const float* __restrict__ Cg,
                          __hip_bfloat16* __restrict__ CwB) {
    int row = blockIdx.x;        // 0..127 = c*32+r
    int lane = threadIdx.x;      // 64
    float v0 = Cv[row * kD + lane], v1 = Cv[row * kD + 64 + lane];
    float s = v0 * v0 + v1 * v1;
    #pragma unroll
    for (int off = 32; off > 0; off >>= 1) s += __shfl_down(s, off);
    s = __shfl(s, 0);
    float scale = Cg[row] / sqrtf(s);
    CwB[row * kD + lane] = __float2bfloat16(v0 * scale);
    CwB[row * kD + 64 + lane] = __float2bfloat16(v1 * scale);
}

// ---------------- MFMA GRU step ----------------
// 512 threads = 8 waves; block owns 128 cells; wave owns 16 cells (all 192 gates).
// L0: gh0 = h_prev @ wh0^T via MFMA (C rows=cells, cols=gates) -> per-lane combine.
// L1: K=128 concat [h1 | H1init] @ [wx1 | wh1]^T; n-gate split into two K-half accs.
__global__ __launch_bounds__(512) void k_gru(
    const float* __restrict__ x,
    __hip_bfloat16* __restrict__ HcG,        // [65536][64] state in/out
    const __hip_bfloat16* __restrict__ H1b,  // [512][64]
    const __hip_bfloat16* __restrict__ W0g,  // [192][64]
    const __hip_bfloat16* __restrict__ W1g,  // [192][128]
    const float* __restrict__ wx0, const float* __restrict__ bx0,
    const float* __restrict__ bh0, const float* __restrict__ bx1,
    const float* __restrict__ bh1,
    __hip_bfloat16* __restrict__ XPT, int t)
{
    __shared__ __align__(16) short W0s[192 * 64];    // 24KB
    __shared__ __align__(16) short W1s[192 * 128];   // 48KB
    __shared__ __align__(16) short HcS[128 * 64];    // 16KB
    __shared__ __align__(16) short H1S[128 * 64];    // 16KB
    __shared__ __align__(16) short HlS[128 * 64];    // 16KB
    __shared__ float xsh[128];

    const int tid = threadIdx.x;
    const int blk = blockIdx.x;
    const int w = tid >> 6, lane = tid & 63;
    const int lr = lane & 15, lq = lane >> 4;
    const int b = blk >> 2;
    const int mBlk = (blk & 3) * 128;

    // ---- stage (all gl_lds16, XOR chunk-swizzle on global source) ----
    #pragma unroll
    for (int it = 0; it < 3; it++) {                  // W0s: 1536 chunks
        int cid = it * 512 + tid; int row = cid >> 3, c = cid & 7;
        gl_lds16(W0g + row * 64 + ((c ^ (row & 7)) * 8), W0s + cid * 8);
    }
    #pragma unroll
    for (int it = 0; it < 6; it++) {                  // W1s: 3072 chunks
        int cid = it * 512 + tid; int row = cid >> 4, c = cid & 15;
        gl_lds16(W1g + row * 128 + ((c ^ (row & 15)) * 8), W1s + cid * 8);
    }
    #pragma unroll
    for (int it = 0; it < 2; it++) {                  // HcS + H1S: 1024 chunks each
        int cid = it * 512 + tid; int row = cid >> 3, c = cid & 7;
        gl_lds16(HcG + (size_t)(blk * 128 + row) * 64 + ((c ^ (row & 7)) * 8), HcS + cid * 8);
        gl_lds16(H1b + (size_t)(mBlk + row) * 64 + ((c ^ (row & 7)) * 8), H1S + cid * 8);
    }
    if (tid < 128) xsh[tid] = x[((size_t)b * kW + t) * kM + mBlk + tid];
    __syncthreads();

    const int cl = w * 16 + lr;      // A-fragment row (cell) for this lane

    // ---- Layer 0 MFMA: 12 gate-tiles x K=64 ----
    bf16x8 a0[2];
    a0[0] = *(const bf16x8*)&HcS[cl * 64 + ((lq ^ (cl & 7)) * 8)];
    a0[1] = *(const bf16x8*)&HcS[cl * 64 + (((4 + lq) ^ (cl & 7)) * 8)];
    f32x4 aR[4] = {}, aZ[4] = {}, aN[4] = {};
    #pragma unroll
    for (int kc = 0; kc < 2; kc++) {
        #pragma unroll
        for (int gt = 0; gt < 4; gt++) {
            const int gR = gt * 16 + lr;
            const int gZ = 64 + gt * 16 + lr;
            const int gN = 128 + gt * 16 + lr;
            bf16x8 bR = *(const bf16x8*)&W0s[gR * 64 + (((kc * 4 + lq) ^ (gR & 7)) * 8)];
            bf16x8 bZ = *(const bf16x8*)&W0s[gZ * 64 + (((kc * 4 + lq) ^ (gZ & 7)) * 8)];
            bf16x8 bN = *(const bf16x8*)&W0s[gN * 64 + (((kc * 4 + lq) ^ (gN & 7)) * 8)];
            aR[gt] = __builtin_amdgcn_mfma_f32_16x16x32_bf16(a0[kc], bR, aR[gt], 0, 0, 0);
            aZ[gt] = __builtin_amdgcn_mfma_f32_16x16x32_bf16(a0[kc], bZ, aZ[gt], 0, 0, 0);
            aN[gt] = __builtin_amdgcn_mfma_f32_16x16x32_bf16(a0[kc], bN, aN[gt], 0, 0, 0);
        }
    }

    // ---- Layer 0 combine (per-lane: cells lq*4+r, unit i = gt*16+lr) ----
    #pragma unroll
    for (int gt = 0; gt < 4; gt++) {
        const int i = gt * 16 + lr;
        const float wxr = wx0[i], wxz = wx0[64 + i], wxn = wx0[128 + i];
        const float bsr = bx0[i] + bh0[i];
        const float bsz = bx0[64 + i] + bh0[64 + i];
        const float bxn = bx0[128 + i], bhn = bh0[128 + i];
        unsigned short hu[4];
        #pragma unroll
        for (int r2 = 0; r2 < 4; r2++) {
            const int clr = w * 16 + lq * 4 + r2;
            const float xv = xsh[clr];
            float rr = sigmf(aR[gt][r2] + bsr + xv * wxr);
            float zz = sigmf(aZ[gt][r2] + bsz + xv * wxz);
            float nn = tanhf2(bxn + xv * wxn + rr * (aN[gt][r2] + bhn));
            float hp = lds_bf(HcS, clr, i);
            float h1 = nn + zz * (hp - nn);
            unsigned short u = f2bfu(h1);
            HlS[clr * 64 + (((i >> 3) ^ (clr & 7)) * 8) + (i & 7)] = (short)u;
            hu[r2] = u;
        }
        ushort4 pk; pk.x = hu[0]; pk.y = hu[1]; pk.z = hu[2]; pk.w = hu[3];
        *(ushort4*)((unsigned short*)XPT + (size_t)i * kNC + b * 512 + mBlk + w * 16 + lq * 4) = pk;
    }

    // ---- Layer 1 MFMA: K=128 concat; n-gate split over K halves ----
    bf16x8 a1[4];
    a1[0] = *(const bf16x8*)&HlS[cl * 64 + ((lq ^ (cl & 7)) * 8)];
    a1[1] = *(const bf16x8*)&HlS[cl * 64 + (((4 + lq) ^ (cl & 7)) * 8)];
    a1[2] = *(const bf16x8*)&H1S[cl * 64 + ((lq ^ (cl & 7)) * 8)];
    a1[3] = *(const bf16x8*)&H1S[cl * 64 + (((4 + lq) ^ (cl & 7)) * 8)];
    f32x4 cR[4] = {}, cZ[4] = {}, cNX[4] = {}, cNH[4] = {};
    #pragma unroll
    for (int kc = 0; kc < 4; kc++) {
        #pragma unroll
        for (int gt = 0; gt < 4; gt++) {
            const int gR = gt * 16 + lr;
            const int gZ = 64 + gt * 16 + lr;
            const int gN = 128 + gt * 16 + lr;
            bf16x8 bR = *(const bf16x8*)&W1s[gR * 128 + (((kc * 4 + lq) ^ (gR & 15)) * 8)];
            bf16x8 bZ = *(const bf16x8*)&W1s[gZ * 128 + (((kc * 4 + lq) ^ (gZ & 15)) * 8)];
            bf16x8 bN = *(const bf16x8*)&W1s[gN * 128 + (((kc * 4 + lq) ^ (gN & 15)) * 8)];
            cR[gt] = __builtin_amdgcn_mfma_f32_16x16x32_bf16(a1[kc], bR, cR[gt], 0, 0, 0);
            cZ[gt] = __builtin_amdgcn_mfma_f32_16x16x32_bf16(a1[kc], bZ, cZ[gt], 0, 0, 0);
            if (kc < 2) cNX[gt] = __builtin_amdgcn_mfma_f32_16x16x32_bf16(a1[kc], bN, cNX[gt], 0, 0, 0);
            else        cNH[gt] = __builtin_amdgcn_mfma_f32_16x16x32_bf16(a1[kc], bN, cNH[gt], 0, 0, 0);
        }
    }

    // ---- Layer 1 combine ----
    #pragma unroll
    for (int gt = 0; gt < 4; gt++) {
        const int i = gt * 16 + lr;
        const float bsr = bx1[i] + bh1[i];
        const float bsz = bx1[64 + i] + bh1[64 + i];
        const float bxn = bx1[128 + i], bhn = bh1[128 + i];
        unsigned short hu[4];
        #pragma unroll
        for (int r2 = 0; r2 < 4; r2++) {
            const int clr = w * 16 + lq * 4 + r2;
            float rr = sigmf(cR[gt][r2] + bsr);
            float zz = sigmf(cZ[gt][r2] + bsz);
            float nn = tanhf2(cNX[gt][r2] + bxn + rr * (cNH[gt][r2] + bhn));
            float h01 = lds_bf(H1S, clr, i);
            float h2 = nn + zz * (h01 - nn);
            unsigned short u = f2bfu(h2);
            hu[r2] = u;
            ((unsigned short*)HcG)[(size_t)(blk * 128 + clr) * 64 + i] = u;   // next-step state
        }
        ushort4 pk; pk.x = hu[0]; pk.y = hu[1]; pk.z = hu[2]; pk.w = hu[3];
        *(ushort4*)((unsigned short*)XPT + (size_t)(64 + i) * kNC + b * 512 + mBlk + w * 16 + lq * 4) = pk;
    }
}

// ---------------- MFMA GEMM: [16384 x 512]bf16 @ [512 x 576]bf16 ----------------
__global__ __launch_bounds__(256) void k_gemm(
    const __hip_bfloat16* __restrict__ X, const __hip_bfloat16* __restrict__ BT,
    const float* __restrict__ Ab, __hip_bfloat16* __restrict__ XP0h,
    float* __restrict__ Abuf)
{
    __shared__ __align__(16) short As[128][64];   // [row][k] 16KB
    __shared__ __align__(16) short Bs[64][64];    // [col][k] 8KB
    const int tid = threadIdx.x;
    const int r0 = blockIdx.x * 128;
    const int n0 = blockIdx.y * 64;
    const int wave = tid >> 6, lane = tid & 63;
    const int wm = wave >> 1, wn = wave & 1;      // 2x2 waves, 64x32 tile each
    const int lr = lane & 15, lq = lane >> 4;

    f32x4 acc[4][2] = {};

    for (int kk = 0; kk < 512; kk += 64) {
        __syncthreads();
        #pragma unroll
        for (int it = 0; it < 4; it++) {
            int cid = it * 256 + tid;
            int row = cid >> 3, c = cid & 7;
            int cg = c ^ (row & 7);
            gl_lds16(X + ((size_t)(r0 + row) * kM + kk + cg * 8), &As[0][0] + cid * 8);
        }
        #pragma unroll
        for (int it = 0; it < 2; it++) {
            int cid = it * 256 + tid;
            int col = cid >> 3, c = cid & 7;
            int cg = c ^ (col & 7);
            gl_lds16(BT + ((size_t)(n0 + col) * kM + kk + cg * 8), &Bs[0][0] + cid * 8);
        }
        __syncthreads();   // drains vmcnt(0) -> staged data visible
        #pragma unroll
        for (int w2 = 0; w2 < 2; w2++) {
            bf16x8 af[4], bfr[2];
            #pragma unroll
            for (int fi = 0; fi < 4; fi++) {
                int row = wm * 64 + fi * 16 + lr;
                int c = (w2 * 4 + lq) ^ (row & 7);
                af[fi] = *(const bf16x8*)&As[row][c * 8];
            }
            #pragma unroll
            for (int fj = 0; fj < 2; fj++) {
                int col = wn * 32 + fj * 16 + lr;
                int c = (w2 * 4 + lq) ^ (col & 7);
                bfr[fj] = *(const bf16x8*)&Bs[col][c * 8];
            }
            #pragma unroll
            for (int fi = 0; fi < 4; fi++)
                #pragma unroll
                for (int fj = 0; fj < 2; fj++)
                    acc[fi][fj] = __builtin_amdgcn_mfma_f32_16x16x32_bf16(
                        af[fi], bfr[fj], acc[fi][fj], 0, 0, 0);
        }
    }
    if (n0 < kM) {
        #pragma unroll
        for (int fi = 0; fi < 4; fi++)
            #pragma unroll
            for (int fj = 0; fj < 2; fj++) {
                int colg = n0 + wn * 32 + fj * 16 + lr;
                #pragma unroll
                for (int r = 0; r < 4; r++) {
                    int rowg = r0 + wm * 64 + fi * 16 + lq * 4 + r;
                    XP0h[(size_t)rowg * kM + colg] = __float2bfloat16(fmaxf(acc[fi][fj][r], 0.f));
                }
            }
    } else {
        #pragma unroll
        for (int fi = 0; fi < 4; fi++)
            #pragma unroll
            for (int fj = 0; fj < 2; fj++) {
                int cl = wn * 32 + fj * 16 + lr;
                float ab = Ab[cl];
                #pragma unroll
                for (int r = 0; r < 4; r++) {
                    int rowg = r0 + wm * 64 + fi * 16 + lq * 4 + r;
                    Abuf[(size_t)rowg * 64 + cl] = acc[fi][fj][r] + ab;
                }
            }
    }
}

// ---------------- fused bmid / relu / y / out (MFMA) ----------------
__global__ __launch_bounds__(256) void k_fused(
    const __hip_bfloat16* __restrict__ XP0h, const float* __restrict__ Abuf,
    const __hip_bfloat16* __restrict__ BwNh, const __hip_bfloat16* __restrict__ CwB,
    const float* __restrict__ Cb, const float* __restrict__ FRw,
    const float* __restrict__ FRb, float* __restrict__ OUT, int t)
{
    __shared__ __align__(16) short CwS[32][136];     // 8.5KB, pad-8 rows
    __shared__ __align__(16) short Xr[4][32][128];   // 32KB, per-wave [m][d] bf16
    const int tid = threadIdx.x;
    const int b = blockIdx.x;
    const int c = blockIdx.y >> 1, mh = blockIdx.y & 1;
    const int w = tid >> 6, lane = tid & 63;
    const int lr = lane & 15, lq = lane >> 4;

    // stage Cw tile [32 r][128 d]
    #pragma unroll
    for (int it = 0; it < 2; it++) {
        int cid = it * 256 + tid;                    // 512 chunks of 8 bf16
        int r = cid >> 4, ch = cid & 15;
        *(float4*)&CwS[r][ch * 8] =
            *(const float4*)&CwB[((size_t)c * kRD + r) * kD + ch * 8];
    }

    // persistent A-frags for stage 1: af[dt], row d = dt*16+lr, k = l (padded 32)
    bf16x8 af[8];
    #pragma unroll
    for (int dt = 0; dt < 8; dt++) {
        bf16x8 v = {};
        if (lq < 2) {
            const float* ap = &Abuf[((size_t)(dt * 16 + lr) * kB + b) * 64 + c * 16 + lq * 8];
            float4 a0 = *(const float4*)ap;
            float4 a1 = *(const float4*)(ap + 4);
            v[0] = (short)f2bfu(a0.x); v[1] = (short)f2bfu(a0.y);
            v[2] = (short)f2bfu(a0.z); v[3] = (short)f2bfu(a0.w);
            v[4] = (short)f2bfu(a1.x); v[5] = (short)f2bfu(a1.y);
            v[6] = (short)f2bfu(a1.z); v[7] = (short)f2bfu(a1.w);
        } else if (lq == 2) {
            v[0] = (short)0x3F80;     // 1.0 at l=16 -> bias column
        }
        af[dt] = v;
    }
    __syncthreads();

    // persistent B-frags for stage 2: cwf[rt][s], row r = rt*16+lr, k d = s*32+lq*8
    bf16x8 cwf[2][4];
    #pragma unroll
    for (int rt = 0; rt < 2; rt++)
        #pragma unroll
        for (int s = 0; s < 4; s++)
            cwf[rt][s] = *(const bf16x8*)&CwS[rt * 16 + lr][s * 32 + lq * 8];

    const float cbv0 = Cb[c * kRD + lr];
    const float cbv1 = Cb[c * kRD + 16 + lr];
    const int mw0 = mh * 256 + w * 64;

    for (int ms = 0; ms < 2; ms++) {
        const int mbase = mw0 + ms * 32;
        // ---- stage 1 ----
        #pragma unroll
        for (int mt2 = 0; mt2 < 2; mt2++) {
            const int mg = mbase + mt2 * 16 + lr;    // D col = m
            const int mloc = mt2 * 16 + lr;
            bf16x8 bf1 = *(const bf16x8*)&BwNh[((size_t)c * kM + mg) * 32 + lq * 8];
            f32x4 acc1[8] = {};
            #pragma unroll
            for (int dt = 0; dt < 8; dt++)
                acc1[dt] = __builtin_amdgcn_mfma_f32_16x16x32_bf16(af[dt], bf1, acc1[dt], 0, 0, 0);
            // + x_p0, relu, pack bf16, swizzled LDS write (wave-private)
            #pragma unroll
            for (int dt = 0; dt < 8; dt++) {
                const int d0 = dt * 16 + lq * 4;     // D row = d
                float v0 = acc1[dt][0] + __bfloat162float(XP0h[((size_t)(d0 + 0) * kB + b) * kM + mg]);
                float v1 = acc1[dt][1] + __bfloat162float(XP0h[((size_t)(d0 + 1) * kB + b) * kM + mg]);
                float v2 = acc1[dt][2] + __bfloat162float(XP0h[((size_t)(d0 + 2) * kB + b) * kM + mg]);
                float v3 = acc1[dt][3] + __bfloat162float(XP0h[((size_t)(d0 + 3) * kB + b) * kM + mg]);
                unsigned int lo = (unsigned int)f2bfu(fmaxf(v0, 0.f)) |
                                  ((unsigned int)f2bfu(fmaxf(v1, 0.f)) << 16);
                unsigned int hi = (unsigned int)f2bfu(fmaxf(v2, 0.f)) |
                                  ((unsigned int)f2bfu(fmaxf(v3, 0.f)) << 16);
                const int c16 = dt * 2 + (lq >> 1), half = lq & 1;
                const int col = ((c16 ^ (mloc & 7)) * 8) + half * 4;   // in shorts
                uint2 pk; pk.x = lo; pk.y = hi;
                *(uint2*)&Xr[w][mloc][col] = pk;
            }
        }
        // ---- stage 2 ----
        #pragma unroll
        for (int mt2 = 0; mt2 < 2; mt2++) {
            const int mloc = mt2 * 16 + lr;          // A row = m
            bf16x8 xa[4];
            #pragma unroll
            for (int s = 0; s < 4; s++) {
                const int c16 = s * 4 + lq;
                xa[s] = *(const bf16x8*)&Xr[w][mloc][(c16 ^ (mloc & 7)) * 8];
            }
            float po0 = 0.f, po1 = 0.f, po2 = 0.f, po3 = 0.f;
            #pragma unroll
            for (int rt = 0; rt < 2; rt++) {
                f32x4 a2 = {};
                #pragma unroll
                for (int s = 0; s < 4; s++)
                    a2 = __builtin_amdgcn_mfma_f32_16x16x32_bf16(xa[s], cwf[rt][s], a2, 0, 0, 0);
                const float cb = rt ? cbv1 : cbv0;
                const int r = rt * 16 + lr;          // D col = r
                const int mrow = mbase + mt2 * 16 + lq * 4;  // D row = m
                po0 = fmaf(sigmf(a2[0] + cb), FRw[((size_t)c * kM + mrow + 0) * kRD + r], po0);
                po1 = fmaf(sigmf(a2[1] + cb), FRw[((size_t)c * kM + mrow + 1) * kRD + r], po1);
                po2 = fmaf(sigmf(a2[2] + cb), FRw[((size_t)c * kM + mrow + 2) * kRD + r], po2);
                po3 = fmaf(sigmf(a2[3] + cb), FRw[((size_t)c * kM + mrow + 3) * kRD + r], po3);
            }
            // reduce over the 16-lane r-group
            #pragma unroll
            for (int off = 8; off > 0; off >>= 1) {
                po0 += __shfl_xor(po0, off);
                po1 += __shfl_xor(po1, off);
                po2 += __shfl_xor(po2, off);
                po3 += __shfl_xor(po3, off);
            }
            if (lr == 0) {
                const int mo = mbase + mt2 * 16 + lq * 4;
                const float* frb = &FRb[c * kM + mo];
                float4 o;
                o.x = po0 + frb[0]; o.y = po1 + frb[1];
                o.z = po2 + frb[2]; o.w = po3 + frb[3];
                *(float4*)&OUT[((size_t)(c * kB + b) * kW + t) * kM + mo] = o;
            }
        }
    }
}

// ---------------- launch ----------------
extern "C" void kernel_launch(void* const* d_in, const int* in_sizes, int n_in,
                              void* d_out, int out_size, void* d_ws, size_t ws_size,
                              hipStream_t stream) {
    const float* x    = (const float*)d_in[0];
    const float* Hini = (const float*)d_in[1];
    const float* G    = (const float*)d_in[2];
    const float* wx0  = (const float*)d_in[3];
    const float* wh0  = (const float*)d_in[4];
    const float* bx0  = (const float*)d_in[5];
    const float* bh0  = (const float*)d_in[6];
    const float* wx1  = (const float*)d_in[7];
    const float* wh1  = (const float*)d_in[8];
    const float* bx1  = (const float*)d_in[9];
    const float* bh1  = (const float*)d_in[10];
    const float* A_v  = (const float*)d_in[11];
    const float* A_g  = (const float*)d_in[12];
    const float* A_b  = (const float*)d_in[13];
    const float* B_v  = (const float*)d_in[14];
    const float* B_g  = (const float*)d_in[15];
    const float* B_b  = (const float*)d_in[16];
    const float* C_v  = (const float*)d_in[17];
    const float* C_g  = (const float*)d_in[18];
    const float* C_b  = (const float*)d_in[19];
    const float* FR_w = (const float*)d_in[20];
    const float* FR_b = (const float*)d_in[21];
    float* out = (float*)d_out;

    char* w = (char*)d_ws;
    __hip_bfloat16* HcG  = (__hip_bfloat16*)w; w += (size_t)kNC * 64 * 2;   // 8MB
    __hip_bfloat16* XPT  = (__hip_bfloat16*)w; w += (size_t)128 * kNC * 2;  // 16MB
    __hip_bfloat16* XP0h = (__hip_bfloat16*)w; w += (size_t)kR * kM * 2;    // 16MB
    float*          Abuf = (float*)w;          w += (size_t)kR * 64 * 4;    // 4MB
    __hip_bfloat16* BT   = (__hip_bfloat16*)w; w += (size_t)kN * kM * 2;    // 576KB
    __hip_bfloat16* H1b  = (__hip_bfloat16*)w; w += (size_t)kM * kH * 2;    // 64KB
    __hip_bfloat16* W0g  = (__hip_bfloat16*)w; w += (size_t)192 * 64 * 2;   // 24KB
    __hip_bfloat16* W1g  = (__hip_bfloat16*)w; w += (size_t)192 * 128 * 2;  // 48KB
    __hip_bfloat16* BwNh = (__hip_bfloat16*)w; w += (size_t)2048 * 32 * 2;  // 128KB
    __hip_bfloat16* CwB  = (__hip_bfloat16*)w; w += (size_t)kC * kRD * kD * 2; // 32KB

    k_initHc<<<16384, 256, 0, stream>>>(Hini, HcG);
    k_h1b<<<128, 256, 0, stream>>>(Hini, H1b);
    k_packW<<<96, 256, 0, stream>>>(wh0, wx1, wh1, W0g, W1g);
    k_buildGT<<<1024, 256, 0, stream>>>(G, BT);
    k_norm_aw<<<64, 64, 0, stream>>>(A_v, A_g, BT);
    k_norm_bw<<<8, 256, 0, stream>>>(B_v, B_g, B_b, BwNh);
    k_norm_cw<<<128, 64, 0, stream>>>(C_v, C_g, CwB);

    for (int t = 0; t < kW; t++) {
        k_gru<<<512, 512, 0, stream>>>(x, HcG, H1b, W0g, W1g,
                                       wx0, bx0, bh0, bx1, bh1, XPT, t);
        k_gemm<<<dim3(128, 9), 256, 0, stream>>>(XPT, BT, A_b, XP0h, Abuf);
        k_fused<<<dim3(128, 8), 256, 0, stream>>>(XP0h, Abuf, BwNh, CwB,
                                                  C_b, FR_w, FR_b, out, t);
    }
}

// Round 6
// 4630.605 us; speedup vs baseline: 8.8993x; 1.1137x over previous
//
#include <hip/hip_runtime.h>
#include <hip/hip_bf16.h>

// Problem constants
constexpr int kB  = 128;   // batch
constexpr int kW  = 64;    // time steps
constexpr int kM  = 512;   // "major" dim
constexpr int kH  = 64;    // GRU hidden
constexpr int kC  = 4;
constexpr int kLR = 16;
constexpr int kRD = 32;
constexpr int kD  = 128;   // L*H
constexpr int kNC = kB * kM;      // 65536 cells
constexpr int kN  = kM + kC * kLR; // 576 GEMM cols (G | Aw^T)

typedef __attribute__((ext_vector_type(8))) short bf16x8;
typedef __attribute__((ext_vector_type(4))) float f32x4;

__device__ __forceinline__ float sigmf(float v) { return 1.f / (1.f + __expf(-v)); }
__device__ __forceinline__ float tanhf2(float v) { float e = __expf(2.f * v); return 1.f - 2.f / (e + 1.f); }

__device__ __forceinline__ unsigned short f2bfu(float f) {
    union { __hip_bfloat16 h; unsigned short u; } cv; cv.h = __float2bfloat16(f); return cv.u;
}
__device__ __forceinline__ float bfu2f(unsigned short s) {
    return __uint_as_float(((unsigned)s) << 16);
}

__device__ __forceinline__ void gl_lds16(const void* g, void* s) {
    __builtin_amdgcn_global_load_lds(
        (const __attribute__((address_space(1))) void*)(g),
        (__attribute__((address_space(3))) void*)(s), 16, 0, 0);
}

// swizzled bf16 element read from a [rows][64] bf16 LDS tile staged with chunk^=(row&7)
__device__ __forceinline__ float lds_bf(const short* base, int row, int i) {
    unsigned short s = (unsigned short)base[row * 64 + (((i >> 3) ^ (row & 7)) << 3) + (i & 7)];
    return bfu2f(s);
}

// ---------------- prologue kernels ----------------

// HcG[cell][j] = bf16(H_init[0, m, j])   (cell = b*512 + m)
__global__ void k_initHc(const float* __restrict__ Hini, __hip_bfloat16* __restrict__ HcG) {
    int id = blockIdx.x * 256 + threadIdx.x;          // 65536*64
    int cell = id >> 6, j = id & 63;
    int m = cell & (kM - 1);
    HcG[id] = __float2bfloat16(Hini[m * kH + j]);
}

// H1b[m][j] = bf16(H_init[1, m, j])
__global__ void k_h1b(const float* __restrict__ Hini, __hip_bfloat16* __restrict__ H1b) {
    int id = blockIdx.x * 256 + threadIdx.x;          // 512*64
    H1b[id] = __float2bfloat16(Hini[(kM + (id >> 6)) * kH + (id & 63)]);
}

// W0g[192][64] = bf16(wh0); W1g[192][128] = bf16([wx1 | wh1])
__global__ void k_packW(const float* __restrict__ wh0, const float* __restrict__ wx1,
                        const float* __restrict__ wh1, __hip_bfloat16* __restrict__ W0g,
                        __hip_bfloat16* __restrict__ W1g) {
    int id = blockIdx.x * 256 + threadIdx.x;          // 192*128
    int r = id >> 7, ci = id & 127;
    W1g[id] = __float2bfloat16(ci < 64 ? wx1[r * 64 + ci] : wh1[r * 64 + ci - 64]);
    if (ci < 64) W0g[r * 64 + ci] = __float2bfloat16(wh0[r * 64 + ci]);
}

// BT[n][k] = G[k][n] in bf16 for n<512 (GEMM B pre-transposed, k contiguous)
__global__ void k_buildGT(const float* __restrict__ G, __hip_bfloat16* __restrict__ BT) {
    int id = blockIdx.x * 256 + threadIdx.x;          // 512*512
    int n = id >> 9, k = id & (kM - 1);
    BT[n * kM + k] = __float2bfloat16(G[k * kM + n]);
}

// weight-norm A into BT rows 512..575: BT[512+cl][m] = A_g*A_v/||A_v|| (bf16)
__global__ void k_norm_aw(const float* __restrict__ Av, const float* __restrict__ Ag,
                          __hip_bfloat16* __restrict__ BT) {
    int row = blockIdx.x;        // 0..63 = c*16+l
    int lane = threadIdx.x;      // 64
    float v[8]; float s = 0.f;
    #pragma unroll
    for (int q = 0; q < 8; q++) { v[q] = Av[row * kM + q * 64 + lane]; s += v[q] * v[q]; }
    #pragma unroll
    for (int off = 32; off > 0; off >>= 1) s += __shfl_down(s, off);
    s = __shfl(s, 0);
    float scale = Ag[row] / sqrtf(s);
    #pragma unroll
    for (int q = 0; q < 8; q++)
        BT[(kM + row) * kM + q * 64 + lane] = __float2bfloat16(v[q] * scale);
}

// weight-norm B -> bf16 [c*512+m][32]: l<16 = Bw, l==16 = B_b, rest 0
__global__ void k_norm_bw(const float* __restrict__ Bv, const float* __restrict__ Bg,
                          const float* __restrict__ Bb, __hip_bfloat16* __restrict__ BwNh) {
    int row = blockIdx.x * 256 + threadIdx.x;   // 0..2047 = c*512+m
    float v[16]; float s = 0.f;
    #pragma unroll
    for (int l = 0; l < 16; l++) { v[l] = Bv[row * 16 + l]; s += v[l] * v[l]; }
    float scale = Bg[row] / sqrtf(s);
    #pragma unroll
    for (int l = 0; l < 16; l++) BwNh[row * 32 + l] = __float2bfloat16(v[l] * scale);
    BwNh[row * 32 + 16] = __float2bfloat16(Bb[row]);
    #pragma unroll
    for (int l = 17; l < 32; l++) BwNh[row * 32 + l] = __float2bfloat16(0.f);
}

// weight-norm C -> bf16 [c*32+r][128 d] (natural C_v layout)
__global__ void k_norm_cw(const float* __restrict__ Cv, const float* __restrict__ Cg,
                          __hip_bfloat16* __restrict__ CwB) {
    int row = blockIdx.x;        // 0..127 = c*32+r
    int lane = threadIdx.x;      // 64
    float v0 = Cv[row * kD + lane], v1 = Cv[row * kD + 64 + lane];
    float s = v0 * v0 + v1 * v1;
    #pragma unroll
    for (int off = 32; off > 0; off >>= 1) s += __shfl_down(s, off);
    s = __shfl(s, 0);
    float scale = Cg[row] / sqrtf(s);
    CwB[row * kD + lane] = __float2bfloat16(v0 * scale);
    CwB[row * kD + 64 + lane] = __float2bfloat16(v1 * scale);
}

// ---------------- MFMA GRU step ----------------
// 512 threads = 8 waves; block owns 128 cells; wave owns 16 cells (all 192 gates).
// XPT layout: [b*128 + d][m]  (d<64 = h1, d>=64 = h2) -> GEMM A rows for k_tail.
__global__ __launch_bounds__(512) void k_gru(
    const float* __restrict__ x,
    __hip_bfloat16* __restrict__ HcG,        // [65536][64] state in/out
    const __hip_bfloat16* __restrict__ H1b,  // [512][64]
    const __hip_bfloat16* __restrict__ W0g,  // [192][64]
    const __hip_bfloat16* __restrict__ W1g,  // [192][128]
    const float* __restrict__ wx0, const float* __restrict__ bx0,
    const float* __restrict__ bh0, const float* __restrict__ bx1,
    const float* __restrict__ bh1,
    __hip_bfloat16* __restrict__ XPT, int t)
{
    __shared__ __align__(16) short W0s[192 * 64];    // 24KB
    __shared__ __align__(16) short W1s[192 * 128];   // 48KB
    __shared__ __align__(16) short HcS[128 * 64];    // 16KB
    __shared__ __align__(16) short H1S[128 * 64];    // 16KB
    __shared__ __align__(16) short HlS[128 * 64];    // 16KB
    __shared__ float xsh[128];

    const int tid = threadIdx.x;
    const int blk = blockIdx.x;
    const int w = tid >> 6, lane = tid & 63;
    const int lr = lane & 15, lq = lane >> 4;
    const int b = blk >> 2;
    const int mBlk = (blk & 3) * 128;

    // ---- stage (all gl_lds16, XOR chunk-swizzle on global source) ----
    #pragma unroll
    for (int it = 0; it < 3; it++) {                  // W0s: 1536 chunks
        int cid = it * 512 + tid; int row = cid >> 3, c = cid & 7;
        gl_lds16(W0g + row * 64 + ((c ^ (row & 7)) * 8), W0s + cid * 8);
    }
    #pragma unroll
    for (int it = 0; it < 6; it++) {                  // W1s: 3072 chunks
        int cid = it * 512 + tid; int row = cid >> 4, c = cid & 15;
        gl_lds16(W1g + row * 128 + ((c ^ (row & 15)) * 8), W1s + cid * 8);
    }
    #pragma unroll
    for (int it = 0; it < 2; it++) {                  // HcS + H1S: 1024 chunks each
        int cid = it * 512 + tid; int row = cid >> 3, c = cid & 7;
        gl_lds16(HcG + (size_t)(blk * 128 + row) * 64 + ((c ^ (row & 7)) * 8), HcS + cid * 8);
        gl_lds16(H1b + (size_t)(mBlk + row) * 64 + ((c ^ (row & 7)) * 8), H1S + cid * 8);
    }
    if (tid < 128) xsh[tid] = x[((size_t)b * kW + t) * kM + mBlk + tid];
    __syncthreads();

    const int cl = w * 16 + lr;      // A-fragment row (cell) for this lane

    // ---- Layer 0 MFMA: 12 gate-tiles x K=64 ----
    bf16x8 a0[2];
    a0[0] = *(const bf16x8*)&HcS[cl * 64 + ((lq ^ (cl & 7)) * 8)];
    a0[1] = *(const bf16x8*)&HcS[cl * 64 + (((4 + lq) ^ (cl & 7)) * 8)];
    f32x4 aR[4] = {}, aZ[4] = {}, aN[4] = {};
    #pragma unroll
    for (int kc = 0; kc < 2; kc++) {
        #pragma unroll
        for (int gt = 0; gt < 4; gt++) {
            const int gR = gt * 16 + lr;
            const int gZ = 64 + gt * 16 + lr;
            const int gN = 128 + gt * 16 + lr;
            bf16x8 bR = *(const bf16x8*)&W0s[gR * 64 + (((kc * 4 + lq) ^ (gR & 7)) * 8)];
            bf16x8 bZ = *(const bf16x8*)&W0s[gZ * 64 + (((kc * 4 + lq) ^ (gZ & 7)) * 8)];
            bf16x8 bN = *(const bf16x8*)&W0s[gN * 64 + (((kc * 4 + lq) ^ (gN & 7)) * 8)];
            aR[gt] = __builtin_amdgcn_mfma_f32_16x16x32_bf16(a0[kc], bR, aR[gt], 0, 0, 0);
            aZ[gt] = __builtin_amdgcn_mfma_f32_16x16x32_bf16(a0[kc], bZ, aZ[gt], 0, 0, 0);
            aN[gt] = __builtin_amdgcn_mfma_f32_16x16x32_bf16(a0[kc], bN, aN[gt], 0, 0, 0);
        }
    }

    // ---- Layer 0 combine (per-lane: cells lq*4+r, unit i = gt*16+lr) ----
    #pragma unroll
    for (int gt = 0; gt < 4; gt++) {
        const int i = gt * 16 + lr;
        const float wxr = wx0[i], wxz = wx0[64 + i], wxn = wx0[128 + i];
        const float bsr = bx0[i] + bh0[i];
        const float bsz = bx0[64 + i] + bh0[64 + i];
        const float bxn = bx0[128 + i], bhn = bh0[128 + i];
        unsigned short hu[4];
        #pragma unroll
        for (int r2 = 0; r2 < 4; r2++) {
            const int clr = w * 16 + lq * 4 + r2;
            const float xv = xsh[clr];
            float rr = sigmf(aR[gt][r2] + bsr + xv * wxr);
            float zz = sigmf(aZ[gt][r2] + bsz + xv * wxz);
            float nn = tanhf2(bxn + xv * wxn + rr * (aN[gt][r2] + bhn));
            float hp = lds_bf(HcS, clr, i);
            float h1 = nn + zz * (hp - nn);
            unsigned short u = f2bfu(h1);
            HlS[clr * 64 + (((i >> 3) ^ (clr & 7)) * 8) + (i & 7)] = (short)u;
            hu[r2] = u;
        }
        ushort4 pk; pk.x = hu[0]; pk.y = hu[1]; pk.z = hu[2]; pk.w = hu[3];
        *(ushort4*)((unsigned short*)XPT + (size_t)(b * 128 + i) * kM + mBlk + w * 16 + lq * 4) = pk;
    }

    // ---- Layer 1 MFMA: K=128 concat; n-gate split over K halves ----
    bf16x8 a1[4];
    a1[0] = *(const bf16x8*)&HlS[cl * 64 + ((lq ^ (cl & 7)) * 8)];
    a1[1] = *(const bf16x8*)&HlS[cl * 64 + (((4 + lq) ^ (cl & 7)) * 8)];
    a1[2] = *(const bf16x8*)&H1S[cl * 64 + ((lq ^ (cl & 7)) * 8)];
    a1[3] = *(const bf16x8*)&H1S[cl * 64 + (((4 + lq) ^ (cl & 7)) * 8)];
    f32x4 cR[4] = {}, cZ[4] = {}, cNX[4] = {}, cNH[4] = {};
    #pragma unroll
    for (int kc = 0; kc < 4; kc++) {
        #pragma unroll
        for (int gt = 0; gt < 4; gt++) {
            const int gR = gt * 16 + lr;
            const int gZ = 64 + gt * 16 + lr;
            const int gN = 128 + gt * 16 + lr;
            bf16x8 bR = *(const bf16x8*)&W1s[gR * 128 + (((kc * 4 + lq) ^ (gR & 15)) * 8)];
            bf16x8 bZ = *(const bf16x8*)&W1s[gZ * 128 + (((kc * 4 + lq) ^ (gZ & 15)) * 8)];
            bf16x8 bN = *(const bf16x8*)&W1s[gN * 128 + (((kc * 4 + lq) ^ (gN & 15)) * 8)];
            cR[gt] = __builtin_amdgcn_mfma_f32_16x16x32_bf16(a1[kc], bR, cR[gt], 0, 0, 0);
            cZ[gt] = __builtin_amdgcn_mfma_f32_16x16x32_bf16(a1[kc], bZ, cZ[gt], 0, 0, 0);
            if (kc < 2) cNX[gt] = __builtin_amdgcn_mfma_f32_16x16x32_bf16(a1[kc], bN, cNX[gt], 0, 0, 0);
            else        cNH[gt] = __builtin_amdgcn_mfma_f32_16x16x32_bf16(a1[kc], bN, cNH[gt], 0, 0, 0);
        }
    }

    // ---- Layer 1 combine ----
    #pragma unroll
    for (int gt = 0; gt < 4; gt++) {
        const int i = gt * 16 + lr;
        const float bsr = bx1[i] + bh1[i];
        const float bsz = bx1[64 + i] + bh1[64 + i];
        const float bxn = bx1[128 + i], bhn = bh1[128 + i];
        unsigned short hu[4];
        #pragma unroll
        for (int r2 = 0; r2 < 4; r2++) {
            const int clr = w * 16 + lq * 4 + r2;
            float rr = sigmf(cR[gt][r2] + bsr);
            float zz = sigmf(cZ[gt][r2] + bsz);
            float nn = tanhf2(cNX[gt][r2] + bxn + rr * (cNH[gt][r2] + bhn));
            float h01 = lds_bf(H1S, clr, i);
            float h2 = nn + zz * (h01 - nn);
            unsigned short u = f2bfu(h2);
            hu[r2] = u;
            ((unsigned short*)HcG)[(size_t)(blk * 128 + clr) * 64 + i] = u;   // next-step state
        }
        ushort4 pk; pk.x = hu[0]; pk.y = hu[1]; pk.z = hu[2]; pk.w = hu[3];
        *(ushort4*)((unsigned short*)XPT + (size_t)(b * 128 + 64 + i) * kM + mBlk + w * 16 + lq * 4) = pk;
    }
}

// ---------------- fused GEMM + tail ----------------
// Block = (mseg 0..7, b 0..127); 256 threads = 4 waves (2x2).
// Phase 1 GEMM: C[128 d][128] = XPT[b*128..+127][512K] @ BT cols {mseg's 64 m | 64 a}.
// Phase 2: wn=0 waves scatter relu(m-cols)->xp0L[m][d]; wn=1 scatter (a+A_b)->aL[d][cl].
// Phase 3: wave w = channel c: bmid MFMA + relu -> Xr -> y MFMA -> sigmoid -> FR dot -> OUT.
__global__ __launch_bounds__(256) void k_tail(
    const __hip_bfloat16* __restrict__ X,    // XPT [b*128+d][512]
    const __hip_bfloat16* __restrict__ BT,   // [576][512]
    const float* __restrict__ Ab,
    const __hip_bfloat16* __restrict__ BwNh, // [c*512+m][32]
    const __hip_bfloat16* __restrict__ CwB,  // [c*32+r][128]
    const float* __restrict__ Cb, const float* __restrict__ FRw,
    const float* __restrict__ FRb, float* __restrict__ OUT, int t)
{
    __shared__ __align__(16) short SM[24576];        // 48KB
    short* As   = SM;                // [128 rows][64 k]   (GEMM)
    short* Bs   = SM + 8192;         // [128 cols][64 k]   (GEMM)
    short* xp0L = SM;                // [64 m][128 d]      (tail, aliases As)
    short* aL   = SM + 8192;         // [128 d][64 cl]     (tail, aliases Bs)
    short* Xr   = SM + 16384;        // [4 waves][16 m][128 d]

    const int tid = threadIdx.x;
    const int mseg = blockIdx.x, b = blockIdx.y;
    const int w = tid >> 6, lane = tid & 63;
    const int lr = lane & 15, lq = lane >> 4;
    const int wm = w >> 1, wn = w & 1;

    f32x4 acc[4][4] = {};
    const __hip_bfloat16* Xb = X + (size_t)b * 128 * kM;

    for (int kk = 0; kk < 512; kk += 64) {
        __syncthreads();
        #pragma unroll
        for (int it = 0; it < 4; it++) {             // A: 128 rows x 8 chunks
            int cid = it * 256 + tid;
            int row = cid >> 3, c = cid & 7;
            int cg = c ^ (row & 7);
            gl_lds16(Xb + (size_t)row * kM + kk + cg * 8, As + cid * 8);
        }
        #pragma unroll
        for (int it = 0; it < 4; it++) {             // B: 128 cols x 8 chunks
            int cid = it * 256 + tid;
            int j = cid >> 3, c = cid & 7;
            int cg = c ^ (j & 7);
            int n = (j < 64) ? (mseg * 64 + j) : (448 + j);
            gl_lds16(BT + (size_t)n * kM + kk + cg * 8, Bs + cid * 8);
        }
        __syncthreads();
        #pragma unroll
        for (int w2 = 0; w2 < 2; w2++) {
            bf16x8 af[4], bfr[4];
            #pragma unroll
            for (int fi = 0; fi < 4; fi++) {
                int row = wm * 64 + fi * 16 + lr;
                af[fi] = *(const bf16x8*)&As[row * 64 + (((w2 * 4 + lq) ^ (row & 7)) * 8)];
            }
            #pragma unroll
            for (int fj = 0; fj < 4; fj++) {
                int col = wn * 64 + fj * 16 + lr;
                bfr[fj] = *(const bf16x8*)&Bs[col * 64 + (((w2 * 4 + lq) ^ (col & 7)) * 8)];
            }
            #pragma unroll
            for (int fi = 0; fi < 4; fi++)
                #pragma unroll
                for (int fj = 0; fj < 4; fj++)
                    acc[fi][fj] = __builtin_amdgcn_mfma_f32_16x16x32_bf16(
                        af[fi], bfr[fj], acc[fi][fj], 0, 0, 0);
        }
    }
    __syncthreads();    // all frag reads done; safe to overwrite As/Bs

    // ---- scatter C tile to LDS ----
    if (wn == 0) {
        // m-cols -> relu -> xp0L[m][d], packed 4 d per uint2, chunk-XOR by (m&7)
        #pragma unroll
        for (int fi = 0; fi < 4; fi++) {
            const int d0 = wm * 64 + fi * 16 + lq * 4;
            const int c16 = d0 >> 3, half = lq & 1;
            #pragma unroll
            for (int fj = 0; fj < 4; fj++) {
                const int ml = fj * 16 + lr;
                unsigned lo = (unsigned)f2bfu(fmaxf(acc[fi][fj][0], 0.f)) |
                              ((unsigned)f2bfu(fmaxf(acc[fi][fj][1], 0.f)) << 16);
                unsigned hi = (unsigned)f2bfu(fmaxf(acc[fi][fj][2], 0.f)) |
                              ((unsigned)f2bfu(fmaxf(acc[fi][fj][3], 0.f)) << 16);
                uint2 pk; pk.x = lo; pk.y = hi;
                *(uint2*)&xp0L[ml * 128 + ((c16 ^ (ml & 7)) * 8) + half * 4] = pk;
            }
        }
    } else {
        // a-cols -> +A_b -> aL[d][cl], scalar bf16, chunk-XOR by (d&7)
        #pragma unroll
        for (int fj = 0; fj < 4; fj++) {
            const int clc = fj * 16 + lr;
            const float ab = Ab[clc];
            #pragma unroll
            for (int fi = 0; fi < 4; fi++) {
                #pragma unroll
                for (int r = 0; r < 4; r++) {
                    const int d = wm * 64 + fi * 16 + lq * 4 + r;
                    aL[d * 64 + (((clc >> 3) ^ (d & 7)) * 8) + (clc & 7)] =
                        (short)f2bfu(acc[fi][fj][r] + ab);
                }
            }
        }
    }
    __syncthreads();

    // ---- tail: wave w = channel c ----
    const int c = w;
    bf16x8 af2[8];
    #pragma unroll
    for (int dt = 0; dt < 8; dt++) {
        bf16x8 v = {};
        const int d = dt * 16 + lr;
        if (lq < 2) {
            v = *(const bf16x8*)&aL[d * 64 + (((c * 2 + lq) ^ (d & 7)) * 8)];
        } else if (lq == 2) {
            v[0] = (short)0x3F80;          // 1.0 at k=16 -> bias column
        }
        af2[dt] = v;
    }
    bf16x8 cwf[2][4];
    #pragma unroll
    for (int rt = 0; rt < 2; rt++)
        #pragma unroll
        for (int s = 0; s < 4; s++)
            cwf[rt][s] = *(const bf16x8*)&CwB[((size_t)(c * kRD + rt * 16 + lr)) * kD + s * 32 + lq * 8];
    const float cbv0 = Cb[c * kRD + lr];
    const float cbv1 = Cb[c * kRD + 16 + lr];
    short* Xrw = Xr + w * 2048;

    for (int mt = 0; mt < 4; mt++) {
        const int mg = mseg * 64 + mt * 16 + lr;     // global m (B-frag col)
        bf16x8 bf1 = *(const bf16x8*)&BwNh[((size_t)c * kM + mg) * 32 + lq * 8];
        f32x4 acc1[8] = {};
        #pragma unroll
        for (int dt = 0; dt < 8; dt++)
            acc1[dt] = __builtin_amdgcn_mfma_f32_16x16x32_bf16(af2[dt], bf1, acc1[dt], 0, 0, 0);

        // + x_p0, relu, pack -> Xr (wave-private)
        const int mlT = mt * 16 + lr;                // xp0L row
        #pragma unroll
        for (int dt = 0; dt < 8; dt++) {
            const int c16 = dt * 2 + (lq >> 1), half = lq & 1;
            uint2 xv = *(const uint2*)&xp0L[mlT * 128 + ((c16 ^ (mlT & 7)) * 8) + half * 4];
            float x0 = bfu2f((unsigned short)(xv.x & 0xFFFF));
            float x1 = bfu2f((unsigned short)(xv.x >> 16));
            float x2 = bfu2f((unsigned short)(xv.y & 0xFFFF));
            float x3 = bfu2f((unsigned short)(xv.y >> 16));
            unsigned lo = (unsigned)f2bfu(fmaxf(acc1[dt][0] + x0, 0.f)) |
                          ((unsigned)f2bfu(fmaxf(acc1[dt][1] + x1, 0.f)) << 16);
            unsigned hi = (unsigned)f2bfu(fmaxf(acc1[dt][2] + x2, 0.f)) |
                          ((unsigned)f2bfu(fmaxf(acc1[dt][3] + x3, 0.f)) << 16);
            uint2 pk; pk.x = lo; pk.y = hi;
            *(uint2*)&Xrw[lr * 128 + ((c16 ^ (lr & 7)) * 8) + half * 4] = pk;
        }

        // stage 2: y-logits + sigmoid + FR dot
        bf16x8 xa[4];
        #pragma unroll
        for (int s = 0; s < 4; s++)
            xa[s] = *(const bf16x8*)&Xrw[lr * 128 + (((s * 4 + lq) ^ (lr & 7)) * 8)];
        float po0 = 0.f, po1 = 0.f, po2 = 0.f, po3 = 0.f;
        const int mrow = mseg * 64 + mt * 16 + lq * 4;
        #pragma unroll
        for (int rt = 0; rt < 2; rt++) {
            f32x4 a2 = {};
            #pragma unroll
            for (int s = 0; s < 4; s++)
                a2 = __builtin_amdgcn_mfma_f32_16x16x32_bf16(xa[s], cwf[rt][s], a2, 0, 0, 0);
            const float cb = rt ? cbv1 : cbv0;
            const int r = rt * 16 + lr;
            po0 = fmaf(sigmf(a2[0] + cb), FRw[((size_t)c * kM + mrow + 0) * kRD + r], po0);
            po1 = fmaf(sigmf(a2[1] + cb), FRw[((size_t)c * kM + mrow + 1) * kRD + r], po1);
            po2 = fmaf(sigmf(a2[2] + cb), FRw[((size_t)c * kM + mrow + 2) * kRD + r], po2);
            po3 = fmaf(sigmf(a2[3] + cb), FRw[((size_t)c * kM + mrow + 3) * kRD + r], po3);
        }
        #pragma unroll
        for (int off = 8; off > 0; off >>= 1) {
            po0 += __shfl_xor(po0, off);
            po1 += __shfl_xor(po1, off);
            po2 += __shfl_xor(po2, off);
            po3 += __shfl_xor(po3, off);
        }
        if (lr == 0) {
            const float* frb = &FRb[c * kM + mrow];
            float4 o;
            o.x = po0 + frb[0]; o.y = po1 + frb[1];
            o.z = po2 + frb[2]; o.w = po3 + frb[3];
            *(float4*)&OUT[((size_t)(c * kB + b) * kW + t) * kM + mrow] = o;
        }
    }
}

// ---------------- launch ----------------
extern "C" void kernel_launch(void* const* d_in, const int* in_sizes, int n_in,
                              void* d_out, int out_size, void* d_ws, size_t ws_size,
                              hipStream_t stream) {
    const float* x    = (const float*)d_in[0];
    const float* Hini = (const float*)d_in[1];
    const float* G    = (const float*)d_in[2];
    const float* wx0  = (const float*)d_in[3];
    const float* wh0  = (const float*)d_in[4];
    const float* bx0  = (const float*)d_in[5];
    const float* bh0  = (const float*)d_in[6];
    const float* wx1  = (const float*)d_in[7];
    const float* wh1  = (const float*)d_in[8];
    const float* bx1  = (const float*)d_in[9];
    const float* bh1  = (const float*)d_in[10];
    const float* A_v  = (const float*)d_in[11];
    const float* A_g  = (const float*)d_in[12];
    const float* A_b  = (const float*)d_in[13];
    const float* B_v  = (const float*)d_in[14];
    const float* B_g  = (const float*)d_in[15];
    const float* B_b  = (const float*)d_in[16];
    const float* C_v  = (const float*)d_in[17];
    const float* C_g  = (const float*)d_in[18];
    const float* C_b  = (const float*)d_in[19];
    const float* FR_w = (const float*)d_in[20];
    const float* FR_b = (const float*)d_in[21];
    float* out = (float*)d_out;

    char* w = (char*)d_ws;
    __hip_bfloat16* HcG  = (__hip_bfloat16*)w; w += (size_t)kNC * 64 * 2;   // 8MB
    __hip_bfloat16* XPT  = (__hip_bfloat16*)w; w += (size_t)128 * kNC * 2;  // 16MB
    __hip_bfloat16* BT   = (__hip_bfloat16*)w; w += (size_t)kN * kM * 2;    // 576KB
    __hip_bfloat16* H1b  = (__hip_bfloat16*)w; w += (size_t)kM * kH * 2;    // 64KB
    __hip_bfloat16* W0g  = (__hip_bfloat16*)w; w += (size_t)192 * 64 * 2;   // 24KB
    __hip_bfloat16* W1g  = (__hip_bfloat16*)w; w += (size_t)192 * 128 * 2;  // 48KB
    __hip_bfloat16* BwNh = (__hip_bfloat16*)w; w += (size_t)2048 * 32 * 2;  // 128KB
    __hip_bfloat16* CwB  = (__hip_bfloat16*)w; w += (size_t)kC * kRD * kD * 2; // 32KB

    k_initHc<<<16384, 256, 0, stream>>>(Hini, HcG);
    k_h1b<<<128, 256, 0, stream>>>(Hini, H1b);
    k_packW<<<96, 256, 0, stream>>>(wh0, wx1, wh1, W0g, W1g);
    k_buildGT<<<1024, 256, 0, stream>>>(G, BT);
    k_norm_aw<<<64, 64, 0, stream>>>(A_v, A_g, BT);
    k_norm_bw<<<8, 256, 0, stream>>>(B_v, B_g, B_b, BwNh);
    k_norm_cw<<<128, 64, 0, stream>>>(C_v, C_g, CwB);

    for (int t = 0; t < kW; t++) {
        k_gru<<<512, 512, 0, stream>>>(x, HcG, H1b, W0g, W1g,
                                       wx0, bx0, bh0, bx1, bh1, XPT, t);
        k_tail<<<dim3(8, 128), 256, 0, stream>>>(XPT, BT, A_b, BwNh, CwB,
                                                 C_b, FR_w, FR_b, out, t);
    }
}

// Round 7
// 3947.186 us; speedup vs baseline: 10.4401x; 1.1731x over previous
//
#include <hip/hip_runtime.h>
#include <hip/hip_bf16.h>

// Problem constants
constexpr int kB  = 128;   // batch
constexpr int kW  = 64;    // time steps
constexpr int kM  = 512;   // "major" dim
constexpr int kH  = 64;    // GRU hidden
constexpr int kC  = 4;
constexpr int kLR = 16;
constexpr int kRD = 32;
constexpr int kD  = 128;   // L*H
constexpr int kNC = kB * kM;      // 65536 cells
constexpr int kN  = kM + kC * kLR; // 576 GEMM cols (G | Aw^T)

typedef __attribute__((ext_vector_type(8))) short bf16x8;
typedef __attribute__((ext_vector_type(4))) float f32x4;

__device__ __forceinline__ float sigmf(float v) { return 1.f / (1.f + __expf(-v)); }
__device__ __forceinline__ float tanhf2(float v) { float e = __expf(2.f * v); return 1.f - 2.f / (e + 1.f); }

__device__ __forceinline__ unsigned short f2bfu(float f) {
    union { __hip_bfloat16 h; unsigned short u; } cv; cv.h = __float2bfloat16(f); return cv.u;
}
__device__ __forceinline__ float bfu2f(unsigned short s) {
    return __uint_as_float(((unsigned)s) << 16);
}

__device__ __forceinline__ void gl_lds16(const void* g, void* s) {
    __builtin_amdgcn_global_load_lds(
        (const __attribute__((address_space(1))) void*)(g),
        (__attribute__((address_space(3))) void*)(s), 16, 0, 0);
}

// swizzled bf16 element read from a [rows][64] bf16 LDS tile staged with chunk^=(row&7)
__device__ __forceinline__ float lds_bf(const short* base, int row, int i) {
    unsigned short s = (unsigned short)base[row * 64 + (((i >> 3) ^ (row & 7)) << 3) + (i & 7)];
    return bfu2f(s);
}

// ---------------- prologue kernels ----------------

// HcG[cell][j] = bf16(H_init[0, m, j])   (cell = b*512 + m)
__global__ void k_initHc(const float* __restrict__ Hini, __hip_bfloat16* __restrict__ HcG) {
    int id = blockIdx.x * 256 + threadIdx.x;          // 65536*64
    int cell = id >> 6, j = id & 63;
    int m = cell & (kM - 1);
    HcG[id] = __float2bfloat16(Hini[m * kH + j]);
}

// H1b[m][j] = bf16(H_init[1, m, j])
__global__ void k_h1b(const float* __restrict__ Hini, __hip_bfloat16* __restrict__ H1b) {
    int id = blockIdx.x * 256 + threadIdx.x;          // 512*64
    H1b[id] = __float2bfloat16(Hini[(kM + (id >> 6)) * kH + (id & 63)]);
}

// W0g[192][64] = bf16(wh0); W1g[192][128] = bf16([wx1 | wh1])
__global__ void k_packW(const float* __restrict__ wh0, const float* __restrict__ wx1,
                        const float* __restrict__ wh1, __hip_bfloat16* __restrict__ W0g,
                        __hip_bfloat16* __restrict__ W1g) {
    int id = blockIdx.x * 256 + threadIdx.x;          // 192*128
    int r = id >> 7, ci = id & 127;
    W1g[id] = __float2bfloat16(ci < 64 ? wx1[r * 64 + ci] : wh1[r * 64 + ci - 64]);
    if (ci < 64) W0g[r * 64 + ci] = __float2bfloat16(wh0[r * 64 + ci]);
}

// BT[n][k] = G[k][n] in bf16 for n<512 (GEMM B pre-transposed, k contiguous)
__global__ void k_buildGT(const float* __restrict__ G, __hip_bfloat16* __restrict__ BT) {
    int id = blockIdx.x * 256 + threadIdx.x;          // 512*512
    int n = id >> 9, k = id & (kM - 1);
    BT[n * kM + k] = __float2bfloat16(G[k * kM + n]);
}

// weight-norm A into BT rows 512..575: BT[512+cl][m] = A_g*A_v/||A_v|| (bf16)
__global__ void k_norm_aw(const float* __restrict__ Av, const float* __restrict__ Ag,
                          __hip_bfloat16* __restrict__ BT) {
    int row = blockIdx.x;        // 0..63 = c*16+l
    int lane = threadIdx.x;      // 64
    float v[8]; float s = 0.f;
    #pragma unroll
    for (int q = 0; q < 8; q++) { v[q] = Av[row * kM + q * 64 + lane]; s += v[q] * v[q]; }
    #pragma unroll
    for (int off = 32; off > 0; off >>= 1) s += __shfl_down(s, off);
    s = __shfl(s, 0);
    float scale = Ag[row] / sqrtf(s);
    #pragma unroll
    for (int q = 0; q < 8; q++)
        BT[(kM + row) * kM + q * 64 + lane] = __float2bfloat16(v[q] * scale);
}

// weight-norm B -> bf16 [c*512+m][32]: l<16 = Bw, l==16 = B_b, rest 0
__global__ void k_norm_bw(const float* __restrict__ Bv, const float* __restrict__ Bg,
                          const float* __restrict__ Bb, __hip_bfloat16* __restrict__ BwNh) {
    int row = blockIdx.x * 256 + threadIdx.x;   // 0..2047 = c*512+m
    float v[16]; float s = 0.f;
    #pragma unroll
    for (int l = 0; l < 16; l++) { v[l] = Bv[row * 16 + l]; s += v[l] * v[l]; }
    float scale = Bg[row] / sqrtf(s);
    #pragma unroll
    for (int l = 0; l < 16; l++) BwNh[row * 32 + l] = __float2bfloat16(v[l] * scale);
    BwNh[row * 32 + 16] = __float2bfloat16(Bb[row]);
    #pragma unroll
    for (int l = 17; l < 32; l++) BwNh[row * 32 + l] = __float2bfloat16(0.f);
}

// weight-norm C -> bf16 [c*32+r][128 d] (natural C_v layout)
__global__ void k_norm_cw(const float* __restrict__ Cv, const float* __restrict__ Cg,
                          __hip_bfloat16* __restrict__ CwB) {
    int row = blockIdx.x;        // 0..127 = c*32+r
    int lane = threadIdx.x;      // 64
    float v0 = Cv[row * kD + lane], v1 = Cv[row * kD + 64 + lane];
    float s = v0 * v0 + v1 * v1;
    #pragma unroll
    for (int off = 32; off > 0; off >>= 1) s += __shfl_down(s, off);
    s = __shfl(s, 0);
    float scale = Cg[row] / sqrtf(s);
    CwB[row * kD + lane] = __float2bfloat16(v0 * scale);
    CwB[row * kD + 64 + lane] = __float2bfloat16(v1 * scale);
}

// ---------------- MFMA GRU step ----------------
// 512 threads = 8 waves; block owns 128 cells; wave owns 16 cells (all 192 gates).
// XPT layout: [b*128 + d][m]  (d<64 = h1, d>=64 = h2) -> GEMM A rows for k_tail.
__global__ __launch_bounds__(512) void k_gru(
    const float* __restrict__ x,
    __hip_bfloat16* __restrict__ HcG,        // [65536][64] state in/out
    const __hip_bfloat16* __restrict__ H1b,  // [512][64]
    const __hip_bfloat16* __restrict__ W0g,  // [192][64]
    const __hip_bfloat16* __restrict__ W1g,  // [192][128]
    const float* __restrict__ wx0, const float* __restrict__ bx0,
    const float* __restrict__ bh0, const float* __restrict__ bx1,
    const float* __restrict__ bh1,
    __hip_bfloat16* __restrict__ XPT, int t)
{
    __shared__ __align__(16) short W0s[192 * 64];    // 24KB
    __shared__ __align__(16) short W1s[192 * 128];   // 48KB
    __shared__ __align__(16) short HcS[128 * 64];    // 16KB
    __shared__ __align__(16) short H1S[128 * 64];    // 16KB
    __shared__ __align__(16) short HlS[128 * 64];    // 16KB
    __shared__ float xsh[128];

    const int tid = threadIdx.x;
    const int blk = blockIdx.x;
    const int w = tid >> 6, lane = tid & 63;
    const int lr = lane & 15, lq = lane >> 4;
    const int b = blk >> 2;
    const int mBlk = (blk & 3) * 128;

    // ---- stage (all gl_lds16, XOR chunk-swizzle on global source) ----
    #pragma unroll
    for (int it = 0; it < 3; it++) {                  // W0s: 1536 chunks
        int cid = it * 512 + tid; int row = cid >> 3, c = cid & 7;
        gl_lds16(W0g + row * 64 + ((c ^ (row & 7)) * 8), W0s + cid * 8);
    }
    #pragma unroll
    for (int it = 0; it < 6; it++) {                  // W1s: 3072 chunks
        int cid = it * 512 + tid; int row = cid >> 4, c = cid & 15;
        gl_lds16(W1g + row * 128 + ((c ^ (row & 15)) * 8), W1s + cid * 8);
    }
    #pragma unroll
    for (int it = 0; it < 2; it++) {                  // HcS + H1S: 1024 chunks each
        int cid = it * 512 + tid; int row = cid >> 3, c = cid & 7;
        gl_lds16(HcG + (size_t)(blk * 128 + row) * 64 + ((c ^ (row & 7)) * 8), HcS + cid * 8);
        gl_lds16(H1b + (size_t)(mBlk + row) * 64 + ((c ^ (row & 7)) * 8), H1S + cid * 8);
    }
    if (tid < 128) xsh[tid] = x[((size_t)b * kW + t) * kM + mBlk + tid];
    __syncthreads();

    const int cl = w * 16 + lr;      // A-fragment row (cell) for this lane

    // ---- Layer 0 MFMA: 12 gate-tiles x K=64 ----
    bf16x8 a0[2];
    a0[0] = *(const bf16x8*)&HcS[cl * 64 + ((lq ^ (cl & 7)) * 8)];
    a0[1] = *(const bf16x8*)&HcS[cl * 64 + (((4 + lq) ^ (cl & 7)) * 8)];
    f32x4 aR[4] = {}, aZ[4] = {}, aN[4] = {};
    #pragma unroll
    for (int kc = 0; kc < 2; kc++) {
        #pragma unroll
        for (int gt = 0; gt < 4; gt++) {
            const int gR = gt * 16 + lr;
            const int gZ = 64 + gt * 16 + lr;
            const int gN = 128 + gt * 16 + lr;
            bf16x8 bR = *(const bf16x8*)&W0s[gR * 64 + (((kc * 4 + lq) ^ (gR & 7)) * 8)];
            bf16x8 bZ = *(const bf16x8*)&W0s[gZ * 64 + (((kc * 4 + lq) ^ (gZ & 7)) * 8)];
            bf16x8 bN = *(const bf16x8*)&W0s[gN * 64 + (((kc * 4 + lq) ^ (gN & 7)) * 8)];
            aR[gt] = __builtin_amdgcn_mfma_f32_16x16x32_bf16(a0[kc], bR, aR[gt], 0, 0, 0);
            aZ[gt] = __builtin_amdgcn_mfma_f32_16x16x32_bf16(a0[kc], bZ, aZ[gt], 0, 0, 0);
            aN[gt] = __builtin_amdgcn_mfma_f32_16x16x32_bf16(a0[kc], bN, aN[gt], 0, 0, 0);
        }
    }

    // ---- Layer 0 combine (per-lane: cells lq*4+r, unit i = gt*16+lr) ----
    #pragma unroll
    for (int gt = 0; gt < 4; gt++) {
        const int i = gt * 16 + lr;
        const float wxr = wx0[i], wxz = wx0[64 + i], wxn = wx0[128 + i];
        const float bsr = bx0[i] + bh0[i];
        const float bsz = bx0[64 + i] + bh0[64 + i];
        const float bxn = bx0[128 + i], bhn = bh0[128 + i];
        unsigned short hu[4];
        #pragma unroll
        for (int r2 = 0; r2 < 4; r2++) {
            const int clr = w * 16 + lq * 4 + r2;
            const float xv = xsh[clr];
            float rr = sigmf(aR[gt][r2] + bsr + xv * wxr);
            float zz = sigmf(aZ[gt][r2] + bsz + xv * wxz);
            float nn = tanhf2(bxn + xv * wxn + rr * (aN[gt][r2] + bhn));
            float hp = lds_bf(HcS, clr, i);
            float h1 = nn + zz * (hp - nn);
            unsigned short u = f2bfu(h1);
            HlS[clr * 64 + (((i >> 3) ^ (clr & 7)) * 8) + (i & 7)] = (short)u;
            hu[r2] = u;
        }
        ushort4 pk; pk.x = hu[0]; pk.y = hu[1]; pk.z = hu[2]; pk.w = hu[3];
        *(ushort4*)((unsigned short*)XPT + (size_t)(b * 128 + i) * kM + mBlk + w * 16 + lq * 4) = pk;
    }

    // ---- Layer 1 MFMA: K=128 concat; n-gate split over K halves ----
    bf16x8 a1[4];
    a1[0] = *(const bf16x8*)&HlS[cl * 64 + ((lq ^ (cl & 7)) * 8)];
    a1[1] = *(const bf16x8*)&HlS[cl * 64 + (((4 + lq) ^ (cl & 7)) * 8)];
    a1[2] = *(const bf16x8*)&H1S[cl * 64 + ((lq ^ (cl & 7)) * 8)];
    a1[3] = *(const bf16x8*)&H1S[cl * 64 + (((4 + lq) ^ (cl & 7)) * 8)];
    f32x4 cR[4] = {}, cZ[4] = {}, cNX[4] = {}, cNH[4] = {};
    #pragma unroll
    for (int kc = 0; kc < 4; kc++) {
        #pragma unroll
        for (int gt = 0; gt < 4; gt++) {
            const int gR = gt * 16 + lr;
            const int gZ = 64 + gt * 16 + lr;
            const int gN = 128 + gt * 16 + lr;
            bf16x8 bR = *(const bf16x8*)&W1s[gR * 128 + (((kc * 4 + lq) ^ (gR & 15)) * 8)];
            bf16x8 bZ = *(const bf16x8*)&W1s[gZ * 128 + (((kc * 4 + lq) ^ (gZ & 15)) * 8)];
            bf16x8 bN = *(const bf16x8*)&W1s[gN * 128 + (((kc * 4 + lq) ^ (gN & 15)) * 8)];
            cR[gt] = __builtin_amdgcn_mfma_f32_16x16x32_bf16(a1[kc], bR, cR[gt], 0, 0, 0);
            cZ[gt] = __builtin_amdgcn_mfma_f32_16x16x32_bf16(a1[kc], bZ, cZ[gt], 0, 0, 0);
            if (kc < 2) cNX[gt] = __builtin_amdgcn_mfma_f32_16x16x32_bf16(a1[kc], bN, cNX[gt], 0, 0, 0);
            else        cNH[gt] = __builtin_amdgcn_mfma_f32_16x16x32_bf16(a1[kc], bN, cNH[gt], 0, 0, 0);
        }
    }

    // ---- Layer 1 combine ----
    #pragma unroll
    for (int gt = 0; gt < 4; gt++) {
        const int i = gt * 16 + lr;
        const float bsr = bx1[i] + bh1[i];
        const float bsz = bx1[64 + i] + bh1[64 + i];
        const float bxn = bx1[128 + i], bhn = bh1[128 + i];
        unsigned short hu[4];
        #pragma unroll
        for (int r2 = 0; r2 < 4; r2++) {
            const int clr = w * 16 + lq * 4 + r2;
            float rr = sigmf(cR[gt][r2] + bsr);
            float zz = sigmf(cZ[gt][r2] + bsz);
            float nn = tanhf2(cNX[gt][r2] + bxn + rr * (cNH[gt][r2] + bhn));
            float h01 = lds_bf(H1S, clr, i);
            float h2 = nn + zz * (h01 - nn);
            unsigned short u = f2bfu(h2);
            hu[r2] = u;
            ((unsigned short*)HcG)[(size_t)(blk * 128 + clr) * 64 + i] = u;   // next-step state
        }
        ushort4 pk; pk.x = hu[0]; pk.y = hu[1]; pk.z = hu[2]; pk.w = hu[3];
        *(ushort4*)((unsigned short*)XPT + (size_t)(b * 128 + 64 + i) * kM + mBlk + w * 16 + lq * 4) = pk;
    }
}

// ---------------- fused GEMM + tail ----------------
// Grid dim3(128 b, 8 mseg): linear blk = b + 128*mseg -> blk%8 = b%8, so all 8
// mseg-blocks of one b land on the SAME XCD -> XPT panel (128KB) hits L2.
// K-loop is double-buffered: STAGE(next) issued before compute(cur), one
// __syncthreads (vmcnt drain) per tile.
__global__ __launch_bounds__(256) void k_tail(
    const __hip_bfloat16* __restrict__ X,    // XPT [b*128+d][512]
    const __hip_bfloat16* __restrict__ BT,   // [576][512]
    const float* __restrict__ Ab,
    const __hip_bfloat16* __restrict__ BwNh, // [c*512+m][32]
    const __hip_bfloat16* __restrict__ CwB,  // [c*32+r][128]
    const float* __restrict__ Cb, const float* __restrict__ FRw,
    const float* __restrict__ FRb, float* __restrict__ OUT, int t)
{
    __shared__ __align__(16) short SM[40960];        // 80KB
    // buf0: As [0,8192) Bs [8192,16384); buf1: As [16384,24576) Bs [24576,32768)
    short* xp0L = SM;                // [64 m][128 d]      (tail, aliases buf0 As)
    short* aL   = SM + 8192;         // [128 d][64 cl]     (tail, aliases buf0 Bs)
    short* Xr   = SM + 32768;        // [4 waves][16 m][128 d]

    const int tid = threadIdx.x;
    const int b = blockIdx.x, mseg = blockIdx.y;
    const int w = tid >> 6, lane = tid & 63;
    const int lr = lane & 15, lq = lane >> 4;
    const int wm = w >> 1, wn = w & 1;

    f32x4 acc[4][4] = {};
    const __hip_bfloat16* Xb = X + (size_t)b * 128 * kM;

    auto STAGE = [&](int kk, int buf) {
        short* AsB = SM + buf * 16384;
        short* BsB = AsB + 8192;
        #pragma unroll
        for (int it = 0; it < 4; it++) {             // A: 128 rows x 8 chunks
            int cid = it * 256 + tid;
            int row = cid >> 3, ch = cid & 7;
            int cg = ch ^ (row & 7);
            gl_lds16(Xb + (size_t)row * kM + kk + cg * 8, AsB + cid * 8);
        }
        #pragma unroll
        for (int it = 0; it < 4; it++) {             // B: 128 cols x 8 chunks
            int cid = it * 256 + tid;
            int j = cid >> 3, ch = cid & 7;
            int cg = ch ^ (j & 7);
            int n = (j < 64) ? (mseg * 64 + j) : (448 + j);
            gl_lds16(BT + (size_t)n * kM + kk + cg * 8, BsB + cid * 8);
        }
    };

    STAGE(0, 0);
    __syncthreads();          // drain vmcnt(0): buf0 ready

    int cur = 0;
    for (int ki = 0; ki < 8; ki++) {
        if (ki < 7) STAGE((ki + 1) * 64, cur ^ 1);   // loads in flight over compute
        const short* AsB = SM + cur * 16384;
        const short* BsB = AsB + 8192;
        #pragma unroll
        for (int w2 = 0; w2 < 2; w2++) {
            bf16x8 af[4], bfr[4];
            #pragma unroll
            for (int fi = 0; fi < 4; fi++) {
                int row = wm * 64 + fi * 16 + lr;
                af[fi] = *(const bf16x8*)&AsB[row * 64 + (((w2 * 4 + lq) ^ (row & 7)) * 8)];
            }
            #pragma unroll
            for (int fj = 0; fj < 4; fj++) {
                int col = wn * 64 + fj * 16 + lr;
                bfr[fj] = *(const bf16x8*)&BsB[col * 64 + (((w2 * 4 + lq) ^ (col & 7)) * 8)];
            }
            #pragma unroll
            for (int fi = 0; fi < 4; fi++)
                #pragma unroll
                for (int fj = 0; fj < 4; fj++)
                    acc[fi][fj] = __builtin_amdgcn_mfma_f32_16x16x32_bf16(
                        af[fi], bfr[fj], acc[fi][fj], 0, 0, 0);
        }
        __syncthreads();      // waves done with buf[cur]; next buf staged (vmcnt drained)
        cur ^= 1;
    }

    // ---- scatter C tile to LDS (buf0 region is free: last read was ki=6) ----
    if (wn == 0) {
        // m-cols -> relu -> xp0L[m][d], packed 4 d per uint2, chunk-XOR by (m&7)
        #pragma unroll
        for (int fi = 0; fi < 4; fi++) {
            const int d0 = wm * 64 + fi * 16 + lq * 4;
            const int c16 = d0 >> 3, half = lq & 1;
            #pragma unroll
            for (int fj = 0; fj < 4; fj++) {
                const int ml = fj * 16 + lr;
                unsigned lo = (unsigned)f2bfu(fmaxf(acc[fi][fj][0], 0.f)) |
                              ((unsigned)f2bfu(fmaxf(acc[fi][fj][1], 0.f)) << 16);
                unsigned hi = (unsigned)f2bfu(fmaxf(acc[fi][fj][2], 0.f)) |
                              ((unsigned)f2bfu(fmaxf(acc[fi][fj][3], 0.f)) << 16);
                uint2 pk; pk.x = lo; pk.y = hi;
                *(uint2*)&xp0L[ml * 128 + ((c16 ^ (ml & 7)) * 8) + half * 4] = pk;
            }
        }
    } else {
        // a-cols -> +A_b -> aL[d][cl], scalar bf16, chunk-XOR by (d&7)
        #pragma unroll
        for (int fj = 0; fj < 4; fj++) {
            const int clc = fj * 16 + lr;
            const float ab = Ab[clc];
            #pragma unroll
            for (int fi = 0; fi < 4; fi++) {
                #pragma unroll
                for (int r = 0; r < 4; r++) {
                    const int d = wm * 64 + fi * 16 + lq * 4 + r;
                    aL[d * 64 + (((clc >> 3) ^ (d & 7)) * 8) + (clc & 7)] =
                        (short)f2bfu(acc[fi][fj][r] + ab);
                }
            }
        }
    }
    __syncthreads();

    // ---- tail: wave w = channel c ----
    const int c = w;
    bf16x8 af2[8];
    #pragma unroll
    for (int dt = 0; dt < 8; dt++) {
        bf16x8 v = {};
        const int d = dt * 16 + lr;
        if (lq < 2) {
            v = *(const bf16x8*)&aL[d * 64 + (((c * 2 + lq) ^ (d & 7)) * 8)];
        } else if (lq == 2) {
            v[0] = (short)0x3F80;          // 1.0 at k=16 -> bias column
        }
        af2[dt] = v;
    }
    bf16x8 cwf[2][4];
    #pragma unroll
    for (int rt = 0; rt < 2; rt++)
        #pragma unroll
        for (int s = 0; s < 4; s++)
            cwf[rt][s] = *(const bf16x8*)&CwB[((size_t)(c * kRD + rt * 16 + lr)) * kD + s * 32 + lq * 8];
    const float cbv0 = Cb[c * kRD + lr];
    const float cbv1 = Cb[c * kRD + 16 + lr];
    short* Xrw = Xr + w * 2048;

    for (int mt = 0; mt < 4; mt++) {
        const int mg = mseg * 64 + mt * 16 + lr;     // global m (B-frag col)
        bf16x8 bf1 = *(const bf16x8*)&BwNh[((size_t)c * kM + mg) * 32 + lq * 8];
        f32x4 acc1[8] = {};
        #pragma unroll
        for (int dt = 0; dt < 8; dt++)
            acc1[dt] = __builtin_amdgcn_mfma_f32_16x16x32_bf16(af2[dt], bf1, acc1[dt], 0, 0, 0);

        // + x_p0, relu, pack -> Xr (wave-private)
        const int mlT = mt * 16 + lr;                // xp0L row
        #pragma unroll
        for (int dt = 0; dt < 8; dt++) {
            const int c16 = dt * 2 + (lq >> 1), half = lq & 1;
            uint2 xv = *(const uint2*)&xp0L[mlT * 128 + ((c16 ^ (mlT & 7)) * 8) + half * 4];
            float x0 = bfu2f((unsigned short)(xv.x & 0xFFFF));
            float x1 = bfu2f((unsigned short)(xv.x >> 16));
            float x2 = bfu2f((unsigned short)(xv.y & 0xFFFF));
            float x3 = bfu2f((unsigned short)(xv.y >> 16));
            unsigned lo = (unsigned)f2bfu(fmaxf(acc1[dt][0] + x0, 0.f)) |
                          ((unsigned)f2bfu(fmaxf(acc1[dt][1] + x1, 0.f)) << 16);
            unsigned hi = (unsigned)f2bfu(fmaxf(acc1[dt][2] + x2, 0.f)) |
                          ((unsigned)f2bfu(fmaxf(acc1[dt][3] + x3, 0.f)) << 16);
            uint2 pk; pk.x = lo; pk.y = hi;
            *(uint2*)&Xrw[lr * 128 + ((c16 ^ (lr & 7)) * 8) + half * 4] = pk;
        }

        // stage 2: y-logits + sigmoid + FR dot
        bf16x8 xa[4];
        #pragma unroll
        for (int s = 0; s < 4; s++)
            xa[s] = *(const bf16x8*)&Xrw[lr * 128 + (((s * 4 + lq) ^ (lr & 7)) * 8)];
        float po0 = 0.f, po1 = 0.f, po2 = 0.f, po3 = 0.f;
        const int mrow = mseg * 64 + mt * 16 + lq * 4;
        #pragma unroll
        for (int rt = 0; rt < 2; rt++) {
            f32x4 a2 = {};
            #pragma unroll
            for (int s = 0; s < 4; s++)
                a2 = __builtin_amdgcn_mfma_f32_16x16x32_bf16(xa[s], cwf[rt][s], a2, 0, 0, 0);
            const float cb = rt ? cbv1 : cbv0;
            const int r = rt * 16 + lr;
            po0 = fmaf(sigmf(a2[0] + cb), FRw[((size_t)c * kM + mrow + 0) * kRD + r], po0);
            po1 = fmaf(sigmf(a2[1] + cb), FRw[((size_t)c * kM + mrow + 1) * kRD + r], po1);
            po2 = fmaf(sigmf(a2[2] + cb), FRw[((size_t)c * kM + mrow + 2) * kRD + r], po2);
            po3 = fmaf(sigmf(a2[3] + cb), FRw[((size_t)c * kM + mrow + 3) * kRD + r], po3);
        }
        #pragma unroll
        for (int off = 8; off > 0; off >>= 1) {
            po0 += __shfl_xor(po0, off);
            po1 += __shfl_xor(po1, off);
            po2 += __shfl_xor(po2, off);
            po3 += __shfl_xor(po3, off);
        }
        if (lr == 0) {
            const float* frb = &FRb[c * kM + mrow];
            float4 o;
            o.x = po0 + frb[0]; o.y = po1 + frb[1];
            o.z = po2 + frb[2]; o.w = po3 + frb[3];
            *(float4*)&OUT[((size_t)(c * kB + b) * kW + t) * kM + mrow] = o;
        }
    }
}

// ---------------- launch ----------------
extern "C" void kernel_launch(void* const* d_in, const int* in_sizes, int n_in,
                              void* d_out, int out_size, void* d_ws, size_t ws_size,
                              hipStream_t stream) {
    const float* x    = (const float*)d_in[0];
    const float* Hini = (const float*)d_in[1];
    const float* G    = (const float*)d_in[2];
    const float* wx0  = (const float*)d_in[3];
    const float* wh0  = (const float*)d_in[4];
    const float* bx0  = (const float*)d_in[5];
    const float* bh0  = (const float*)d_in[6];
    const float* wx1  = (const float*)d_in[7];
    const float* wh1  = (const float*)d_in[8];
    const float* bx1  = (const float*)d_in[9];
    const float* bh1  = (const float*)d_in[10];
    const float* A_v  = (const float*)d_in[11];
    const float* A_g  = (const float*)d_in[12];
    const float* A_b  = (const float*)d_in[13];
    const float* B_v  = (const float*)d_in[14];
    const float* B_g  = (const float*)d_in[15];
    const float* B_b  = (const float*)d_in[16];
    const float* C_v  = (const float*)d_in[17];
    const float* C_g  = (const float*)d_in[18];
    const float* C_b  = (const float*)d_in[19];
    const float* FR_w = (const float*)d_in[20];
    const float* FR_b = (const float*)d_in[21];
    float* out = (float*)d_out;

    char* w = (char*)d_ws;
    __hip_bfloat16* HcG  = (__hip_bfloat16*)w; w += (size_t)kNC * 64 * 2;   // 8MB
    __hip_bfloat16* XPT  = (__hip_bfloat16*)w; w += (size_t)128 * kNC * 2;  // 16MB
    __hip_bfloat16* BT   = (__hip_bfloat16*)w; w += (size_t)kN * kM * 2;    // 576KB
    __hip_bfloat16* H1b  = (__hip_bfloat16*)w; w += (size_t)kM * kH * 2;    // 64KB
    __hip_bfloat16* W0g  = (__hip_bfloat16*)w; w += (size_t)192 * 64 * 2;   // 24KB
    __hip_bfloat16* W1g  = (__hip_bfloat16*)w; w += (size_t)192 * 128 * 2;  // 48KB
    __hip_bfloat16* BwNh = (__hip_bfloat16*)w; w += (size_t)2048 * 32 * 2;  // 128KB
    __hip_bfloat16* CwB  = (__hip_bfloat16*)w; w += (size_t)kC * kRD * kD * 2; // 32KB

    k_initHc<<<16384, 256, 0, stream>>>(Hini, HcG);
    k_h1b<<<128, 256, 0, stream>>>(Hini, H1b);
    k_packW<<<96, 256, 0, stream>>>(wh0, wx1, wh1, W0g, W1g);
    k_buildGT<<<1024, 256, 0, stream>>>(G, BT);
    k_norm_aw<<<64, 64, 0, stream>>>(A_v, A_g, BT);
    k_norm_bw<<<8, 256, 0, stream>>>(B_v, B_g, B_b, BwNh);
    k_norm_cw<<<128, 64, 0, stream>>>(C_v, C_g, CwB);

    for (int t = 0; t < kW; t++) {
        k_gru<<<512, 512, 0, stream>>>(x, HcG, H1b, W0g, W1g,
                                       wx0, bx0, bh0, bx1, bh1, XPT, t);
        k_tail<<<dim3(128, 8), 256, 0, stream>>>(XPT, BT, A_b, BwNh, CwB,
                                                 C_b, FR_w, FR_b, out, t);
    }
}